// Round 7
// baseline (2353.800 us; speedup 1.0000x reference)
//
#include <hip/hip_runtime.h>
#include <hip/hip_bf16.h>
#include <math.h>

// Fully self-contained: ZERO d_ws usage. One block per sample; all
// activations live in LDS (64KB union, phase-overlaid). Weight scales are
// recomputed redundantly per block (reads are L2/L3-absorbed).

// ---- LDS union offsets (floats), U[16000] = 64000 B ----
static constexpr int RED  = 0;      // 256   (scale-reduction scratch, pre-phase only)
static constexpr int XQ   = 0;      // 1728  quantized input [3][24][24]
static constexpr int W1Q  = 1728;   // 756   conv1 weights (values)
static constexpr int B1Q  = 2484;   // 28    conv1 bias (values)
static constexpr int C1   = 2512;   // 6776  conv1 out half (14 ch x 22 x 22)
static constexpr int ACT1 = 9288;   // 3388  [28][11][11]
static constexpr int WB   = 0;      // <=6176 conv2/conv3 weight halves (+bias)
static constexpr int C2   = 12676;  // 1944  conv2 out half (24 ch x 9 x 9)
static constexpr int ACT2 = 14620;  // 768   [48][4][4]
static constexpr int ACT3 = 15388;  // 576   [64][3][3] (o,h,w)
static constexpr int A4   = 0;      // 128   fc1 activations
static constexpr int PART = 128;    // 96    head partial sums

__device__ __forceinline__ float loadT(const void* p, size_t i, int isbf) {
    if (isbf) return __bfloat162float(((const __hip_bfloat16*)p)[i]);
    return ((const float*)p)[i];
}
__device__ __forceinline__ float quantw(float v, float s) {      // weight: [-7,7]
    return fminf(fmaxf(rintf(v / s), -7.f), 7.f) * s;
}
__device__ __forceinline__ float qbias(float v, float den) {     // Int32Bias
    return rintf(v / den) * den;
}
__device__ __forceinline__ float qrelu(float v, float s) {       // [0,15]
    return fminf(fmaxf(rintf(fmaxf(v, 0.f) / s), 0.f), 15.f) * s;
}

__global__ void k_beacon(float* out, float code) {
    if (threadIdx.x == 0 && blockIdx.x == 0) out[0] = code;
}

__global__ __launch_bounds__(256) void k_net(
    const void* __restrict__ x,
    const void* __restrict__ w1,  const void* __restrict__ b1,
    const void* __restrict__ w2,  const void* __restrict__ b2,
    const void* __restrict__ w3,  const void* __restrict__ b3,
    const void* __restrict__ fw1, const void* __restrict__ fb1,
    const void* __restrict__ bw,  const void* __restrict__ bb,
    const void* __restrict__ cw,  const void* __restrict__ cb,
    const void* __restrict__ s0p, const void* __restrict__ s1p,
    const void* __restrict__ s2p, const void* __restrict__ s3p,
    const void* __restrict__ s4p, const void* __restrict__ s5p,
    const void* __restrict__ s6p,
    float* __restrict__ outp)
{
    __shared__ float U[16000];
    __shared__ float swsh[8];   // [0..5]=w1,w2,w3,fw1,bw,cw scales; [7]=isbf
    __shared__ float sash[8];   // s_inp,s1,s2,s3,s4,s_bbox,s_conf
    const int tid = threadIdx.x;
    const int b   = blockIdx.x;

    // ---- detect storage format + read activation scales (tid 0) ----
    if (tid == 0) {
        const unsigned short* hb = (const unsigned short*)w1;
        int zeros = 0, sane = 0;
        for (int i = 0; i < 64; ++i) {
            unsigned short u = hb[2 * i];
            float v = __uint_as_float(((unsigned int)u) << 16);
            float a = fabsf(v);
            if (a == 0.f) zeros++;
            else if (a > 1e-8f && a < 1e4f) sane++;
        }
        swsh[7] = (zeros < 40 && sane >= 40) ? 1.f : 0.f;
        const void* sp[7] = { s0p, s1p, s2p, s3p, s4p, s5p, s6p };
        for (int j = 0; j < 7; ++j) {
            float v = *(const float*)sp[j];
            float a = fabsf(v);
            if (!(a > 1e-6f && a < 1e6f)) {
                double d = *(const double*)sp[j];
                double ad = fabs(d);
                if (ad > 1e-6 && ad < 1e6) v = (float)d;
                else {
                    unsigned short u = *(const unsigned short*)sp[j];
                    v = __uint_as_float(((unsigned int)u) << 16);
                }
            }
            sash[j] = v;
        }
    }
    __syncthreads();
    const int isbf = swsh[7] > 0.5f;

    // ---- weight scales: max|w|/7 for 6 tensors (block reduction) ----
    {
        const void* wp[6] = { w1, w2, w3, fw1, bw, cw };
        const int   wn[6] = { 756, 12096, 12288, 73728, 512, 256 };
        for (int j = 0; j < 6; ++j) {
            float m = 0.f;
            for (int i = tid; i < wn[j]; i += 256)
                m = fmaxf(m, fabsf(loadT(wp[j], i, isbf)));
            U[RED + tid] = m; __syncthreads();
            for (int o = 128; o > 0; o >>= 1) {
                if (tid < o) U[RED + tid] = fmaxf(U[RED + tid], U[RED + tid + o]);
                __syncthreads();
            }
            if (tid == 0) swsh[j] = U[RED] / 7.0f;
            __syncthreads();
        }
    }
    const float sa0 = sash[0], sa1 = sash[1], sa2 = sash[2], sa3 = sash[3];
    const float sa4 = sash[4], sab = sash[5], sac = sash[6];
    const float sw1s = swsh[0], sw2s = swsh[1], sw3s = swsh[2];
    const float sw4s = swsh[3], swbs = swsh[4], swcs = swsh[5];

    // ---- phase 1: quant input + conv1 weights/bias ----
    for (int i = tid; i < 1728; i += 256) {
        float v = loadT(x, (size_t)b * 1728 + i, isbf);
        U[XQ + i] = fminf(fmaxf(rintf(v / sa0), -8.f), 7.f) * sa0;   // _q_act_signed
    }
    for (int i = tid; i < 756; i += 256) U[W1Q + i] = quantw(loadT(w1, i, isbf), sw1s);
    {
        const float den = sa0 * sw1s;
        for (int i = tid; i < 28; i += 256) U[B1Q + i] = qbias(loadT(b1, i, isbf), den);
    }
    __syncthreads();

    // conv1 in 2 groups of 14 out-channels; pool(3,2,ceil) + qrelu fused
    for (int g = 0; g < 2; ++g) {
        const int obase = g * 14;
        for (int idx = tid; idx < 308; idx += 256) {        // 14*22 (ol, r)
            const int ol = idx / 22, r = idx % 22, o = obase + ol;
            for (int c = 0; c < 22; ++c) {
                float acc = 0.f;
                #pragma unroll
                for (int ci = 0; ci < 3; ++ci)
                    #pragma unroll
                    for (int kr = 0; kr < 3; ++kr)
                        #pragma unroll
                        for (int kc = 0; kc < 3; ++kc)
                            acc = fmaf(U[XQ + ci * 576 + (r + kr) * 24 + (c + kc)],
                                       U[W1Q + o * 27 + ci * 9 + kr * 3 + kc], acc);
                U[C1 + ol * 484 + r * 22 + c] = acc + U[B1Q + o];
            }
        }
        __syncthreads();
        for (int i = tid; i < 1694; i += 256) {             // 14*121 pooled
            const int ol = i / 121, rem = i % 121, ph = rem / 11, pw = rem % 11;
            const int r0 = 2 * ph, c0 = 2 * pw;
            const int r1 = min(r0 + 3, 22), c1 = min(c0 + 3, 22);   // ceil pad
            float mx = -1e30f;
            for (int r = r0; r < r1; ++r)
                for (int c = c0; c < c1; ++c)
                    mx = fmaxf(mx, U[C1 + ol * 484 + r * 22 + c]);
            U[ACT1 + (obase + ol) * 121 + rem] = qrelu(mx, sa1);
        }
        __syncthreads();
    }

    // ---- phase 2: conv2 (2 halves of 24 out-channels) + pool(3,2) + qrelu ----
    for (int h = 0; h < 2; ++h) {
        const int obase = h * 24;
        for (int i = tid; i < 6048; i += 256)
            U[WB + i] = quantw(loadT(w2, (size_t)h * 6048 + i, isbf), sw2s);
        {
            const float den = sa1 * sw2s;
            for (int i = tid; i < 24; i += 256)
                U[WB + 6048 + i] = qbias(loadT(b2, obase + i, isbf), den);
        }
        __syncthreads();
        for (int idx = tid; idx < 216; idx += 256) {        // 24*9 (ol, r)
            const int ol = idx / 9, r = idx % 9;
            for (int c = 0; c < 9; ++c) {
                float acc = 0.f;
                for (int ci = 0; ci < 28; ++ci)
                    #pragma unroll
                    for (int kr = 0; kr < 3; ++kr)
                        #pragma unroll
                        for (int kc = 0; kc < 3; ++kc)
                            acc = fmaf(U[ACT1 + ci * 121 + (r + kr) * 11 + (c + kc)],
                                       U[WB + ol * 252 + ci * 9 + kr * 3 + kc], acc);
                U[C2 + ol * 81 + r * 9 + c] = acc + U[WB + 6048 + ol];
            }
        }
        __syncthreads();
        for (int i = tid; i < 384; i += 256) {              // 24*16 pooled
            const int ol = i / 16, ph = (i % 16) / 4, pw = i % 4;
            float mx = -1e30f;
            #pragma unroll
            for (int r = 0; r < 3; ++r)
                #pragma unroll
                for (int c = 0; c < 3; ++c)
                    mx = fmaxf(mx, U[C2 + ol * 81 + (2 * ph + r) * 9 + (2 * pw + c)]);
            U[ACT2 + (obase + ol) * 16 + (i % 16)] = qrelu(mx, sa2);
        }
        __syncthreads();
    }

    // ---- phase 3: conv3 (2 halves of 32 out-channels) + qrelu ----
    for (int h = 0; h < 2; ++h) {
        const int obase = h * 32;
        for (int i = tid; i < 6144; i += 256)
            U[WB + i] = quantw(loadT(w3, (size_t)h * 6144 + i, isbf), sw3s);
        {
            const float den = sa2 * sw3s;
            for (int i = tid; i < 32; i += 256)
                U[WB + 6144 + i] = qbias(loadT(b3, obase + i, isbf), den);
        }
        __syncthreads();
        for (int idx = tid; idx < 288; idx += 256) {        // 32*9 (ol, h, w)
            const int ol = idx / 9, hh = (idx % 9) / 3, ww = idx % 3;
            float acc = 0.f;
            for (int ci = 0; ci < 48; ++ci) {
                const int xb2 = ACT2 + ci * 16;
                const int wb2 = WB + ol * 192 + ci * 4;
                acc = fmaf(U[xb2 + hh * 4 + ww],           U[wb2 + 0], acc);
                acc = fmaf(U[xb2 + hh * 4 + ww + 1],       U[wb2 + 1], acc);
                acc = fmaf(U[xb2 + (hh + 1) * 4 + ww],     U[wb2 + 2], acc);
                acc = fmaf(U[xb2 + (hh + 1) * 4 + ww + 1], U[wb2 + 3], acc);
            }
            acc += U[WB + 6144 + ol];
            U[ACT3 + (obase + ol) * 9 + hh * 3 + ww] = qrelu(acc, sa3);
        }
        __syncthreads();
    }

    // ---- phase 4: fc1 (576 -> 128), fw1 streamed coalesced from global ----
    {
        const int wave = tid >> 6, lane = tid & 63;
        const float den = sa3 * sw4s;
        for (int oo = 0; oo < 32; ++oo) {
            const int o = wave * 32 + oo;
            float acc = 0.f;
            #pragma unroll
            for (int j = 0; j < 9; ++j) {
                const int f = lane + 64 * j;                 // ref column: c*9 + w*3 + h
                const int c = f / 9, fw = (f % 9) / 3, fh = f % 3;
                const float av = U[ACT3 + c * 9 + fh * 3 + fw];
                const float wv = quantw(loadT(fw1, (size_t)o * 576 + f, isbf), sw4s);
                acc = fmaf(av, wv, acc);
            }
            #pragma unroll
            for (int off = 32; off > 0; off >>= 1)
                acc += __shfl_down(acc, off);
            if (lane == 0) {
                acc += qbias(loadT(fb1, o, isbf), den);
                U[A4 + o] = qrelu(acc, sa4);
            }
        }
    }
    __syncthreads();

    // ---- phase 5: heads + final signed quant -> f32 out ----
    if (tid < 96) {
        const int d = tid >> 4, g = tid & 15;
        const void* hw = (d < 4) ? bw : cw;
        const int row = (d < 4) ? d : d - 4;
        const float swh = (d < 4) ? swbs : swcs;
        float p = 0.f;
        #pragma unroll
        for (int k = 0; k < 8; ++k) {
            const int kk = g * 8 + k;
            p = fmaf(U[A4 + kk], quantw(loadT(hw, row * 128 + kk, isbf), swh), p);
        }
        U[PART + d * 16 + g] = p;
    }
    __syncthreads();
    if (tid < 6) {
        const int d = tid;
        float acc;
        if (d < 4) acc = qbias(loadT(bb, d, isbf), sa4 * swbs);
        else       acc = qbias(loadT(cb, d - 4, isbf), sa4 * swcs);
        for (int g = 0; g < 16; ++g) acc += U[PART + d * 16 + g];
        if (d < 4) {
            outp[(size_t)b * 4 + d] =
                fminf(fmaxf(rintf(acc / sab), -8.f), 7.f) * sab;
        } else {
            outp[16384 + (size_t)b * 2 + (d - 4)] =
                fminf(fmaxf(rintf(acc / sac), -8.f), 7.f) * sac;
        }
    }
}

extern "C" void kernel_launch(void* const* d_in, const int* in_sizes, int n_in,
                              void* d_out, int out_size, void* d_ws, size_t ws_size,
                              hipStream_t stream)
{
    float* out = (float*)d_out;
    // host-side input-signature validation with error-value beacon
    const int expect[20] = { 7077888, 756, 28, 12096, 48, 12288, 64, 73728, 128,
                             512, 4, 256, 2, 1, 1, 1, 1, 1, 1, 1 };
    if (n_in < 20) {
        k_beacon<<<1, 64, 0, stream>>>(out, 9000.f);
        return;
    }
    for (int i = 0; i < 20; ++i) {
        if (in_sizes[i] != expect[i]) {
            k_beacon<<<1, 64, 0, stream>>>(out, 2000.f + 10.f * i);
            return;
        }
    }
    k_net<<<4096, 256, 0, stream>>>(
        d_in[0], d_in[1], d_in[2], d_in[3], d_in[4], d_in[5], d_in[6],
        d_in[7], d_in[8], d_in[9], d_in[10], d_in[11], d_in[12],
        d_in[13], d_in[14], d_in[15], d_in[16], d_in[17], d_in[18], d_in[19],
        out);
}

// Round 8
// 1082.778 us; speedup vs baseline: 2.1739x; 2.1739x over previous
//
#include <hip/hip_runtime.h>
#include <hip/hip_bf16.h>
#include <math.h>

// ================= shared helpers =================
__device__ __forceinline__ float loadT(const void* p, size_t i, int isbf) {
    if (isbf) return __bfloat162float(((const __hip_bfloat16*)p)[i]);
    return ((const float*)p)[i];
}
__device__ __forceinline__ float quantw(float v, float s) {      // weight: [-7,7]
    return fminf(fmaxf(rintf(v / s), -7.f), 7.f) * s;
}
__device__ __forceinline__ float qbias(float v, float den) {     // Int32Bias
    return rintf(v / den) * den;
}
__device__ __forceinline__ float qrelu(float v, float s) {       // [0,15]
    return fminf(fmaxf(rintf(fmaxf(v, 0.f) / s), 0.f), 15.f) * s;
}

__global__ void k_beacon(float* out, float code) {
    if (threadIdx.x == 0 && blockIdx.x == 0) out[0] = code;
}

// ================= ws layout (floats) =================
// [0..6] activation scales sa0..sa4, sab, sac ; [15] isbf flag
static constexpr int W1V  = 16;     // 756
static constexpr int B1V  = 772;    // 28
static constexpr int W2V  = 800;    // 12096
static constexpr int B2V  = 12896;  // 48
static constexpr int W3V  = 12944;  // 12288
static constexpr int B3V  = 25232;  // 64
static constexpr int FW1V = 25296;  // 73728  [k][o], flatten-folded
static constexpr int FB1V = 99024;  // 128
static constexpr int BWV  = 99152;  // 512
static constexpr int BBV  = 99664;  // 4
static constexpr int CWV  = 99668;  // 256
static constexpr int CBV  = 99924;  // 2  -> end 99926 floats (≈400 KB)

// ================= prep: quantize all weights/biases once =================
__global__ __launch_bounds__(256) void k_prep(
    const void* w1, const void* b1, const void* w2, const void* b2,
    const void* w3, const void* b3, const void* fw1, const void* fb1,
    const void* bw, const void* bb, const void* cw, const void* cb,
    const void* s0p, const void* s1p, const void* s2p, const void* s3p,
    const void* s4p, const void* s5p, const void* s6p,
    float* __restrict__ ws)
{
    __shared__ float red[256];
    __shared__ float sh[2];            // [0]=isbf, [1]=pre-scale for this block
    const int tid = threadIdx.x, blk = blockIdx.x;
    if (tid == 0) {
        const unsigned short* hb = (const unsigned short*)w1;
        int zeros = 0, sane = 0;
        for (int i = 0; i < 64; ++i) {
            unsigned short u = hb[2 * i];
            float v = __uint_as_float(((unsigned int)u) << 16);
            float a = fabsf(v);
            if (a == 0.f) zeros++;
            else if (a > 1e-8f && a < 1e4f) sane++;
        }
        const float isbf = (zeros < 40 && sane >= 40) ? 1.f : 0.f;
        sh[0] = isbf;
        const void* sp[7] = { s0p, s1p, s2p, s3p, s4p, s5p, s6p };
        float sa[7];
        for (int j = 0; j < 7; ++j) {
            float v = *(const float*)sp[j];
            float a = fabsf(v);
            if (!(a > 1e-6f && a < 1e6f)) {
                double d = *(const double*)sp[j];
                double ad = fabs(d);
                if (ad > 1e-6 && ad < 1e6) v = (float)d;
                else {
                    unsigned short u = *(const unsigned short*)sp[j];
                    v = __uint_as_float(((unsigned int)u) << 16);
                }
            }
            sa[j] = v;
        }
        if (blk == 0) {
            for (int j = 0; j < 7; ++j) ws[j] = sa[j];
            ws[15] = isbf;
        }
        const int preidx[6] = { 0, 1, 2, 3, 4, 4 };
        sh[1] = sa[preidx[blk]];
    }
    __syncthreads();
    const int isbf = sh[0] > 0.5f;
    const float pre = sh[1];

    const void* wp[6] = { w1, w2, w3, fw1, bw, cw };
    const void* bp[6] = { b1, b2, b3, fb1, bb, cb };
    const int   wn[6] = { 756, 12096, 12288, 73728, 512, 256 };
    const int   bn[6] = { 28, 48, 64, 128, 4, 2 };
    const int   wo[6] = { W1V, W2V, W3V, FW1V, BWV, CWV };
    const int   bo[6] = { B1V, B2V, B3V, FB1V, BBV, CBV };
    const void* w = wp[blk]; const void* b = bp[blk];
    const int nw = wn[blk], nb = bn[blk], qwo = wo[blk], qbo = bo[blk];

    float m = 0.f;
    for (int i = tid; i < nw; i += 256) m = fmaxf(m, fabsf(loadT(w, i, isbf)));
    red[tid] = m; __syncthreads();
    for (int o = 128; o > 0; o >>= 1) {
        if (tid < o) red[tid] = fmaxf(red[tid], red[tid + o]);
        __syncthreads();
    }
    const float s = red[0] / 7.0f;                 // max|w|/7
    for (int i = tid; i < nw; i += 256) {
        float q = quantw(loadT(w, i, isbf), s);    // quantized VALUE
        int oi = i;
        if (blk == 3) {
            // transpose to [k][o], folding QuantFlatten's transpose(3,2):
            // ref col f = c*9 + w*3 + h ; act3 flat k = c*9 + h*3 + w
            int o = i / 576, f = i % 576;
            int c = f / 9, fw_ = (f % 9) / 3, fh = f % 3;
            oi = (c * 9 + fh * 3 + fw_) * 128 + o;
        }
        ws[qwo + oi] = q;
    }
    const float den = pre * s;                     // Int32Bias scale
    for (int i = tid; i < nb; i += 256)
        ws[qbo + i] = qbias(loadT(b, i, isbf), den);
}

// ================= main fused per-sample kernel (prep path) =================
// LDS union U[8848] = 35392 B -> 4 blocks/CU.
// persistent: ACT1@4116 [28][11][11], ACT2@7504 [48][4][4], ACT3@8272 [64][3][3]
__global__ __launch_bounds__(256, 4) void k_net(
    const void* __restrict__ x, const float* __restrict__ wsr,
    float* __restrict__ outp)
{
    __shared__ float U[8848];
    const int tid = threadIdx.x, b = blockIdx.x;
    const float sa0 = wsr[0], sa1 = wsr[1], sa2 = wsr[2], sa3 = wsr[3];
    const float sa4 = wsr[4], sab = wsr[5], sac = wsr[6];
    const int isbf = wsr[15] > 0.5f;
    constexpr int XQ = 0, W1 = 1800, B1 = 2556;        // XQ [3][24][25] padded
    constexpr int ACT1 = 4116, ACT2 = 7504, ACT3 = 8272;

    // ---- P1: quantize input + stage conv1 weights ----
    for (int i = tid; i < 1728; i += 256) {
        float v = loadT(x, (size_t)b * 1728 + i, isbf);
        const int ci = i / 576, r = (i % 576) / 24, c = i % 24;
        U[XQ + ci * 600 + r * 25 + c] = fminf(fmaxf(rintf(v / sa0), -8.f), 7.f) * sa0;
    }
    for (int i = tid; i < 756; i += 256) U[W1 + i] = wsr[W1V + i];
    if (tid < 28) U[B1 + tid] = wsr[B1V + tid];
    __syncthreads();

    // ---- P2: conv1 + maxpool(3,2,ceil) fused (pool-domain threads) ----
    for (int idx = tid; idx < 3388; idx += 256) {       // 28*11*11
        const int o = idx / 121, rem = idx % 121, ph = rem / 11, pw = rem % 11;
        float wk[27];
        #pragma unroll
        for (int i = 0; i < 27; ++i) wk[i] = U[W1 + o * 27 + i];
        const float bias = U[B1 + o];
        const int r0 = 2 * ph, c0 = 2 * pw;
        const int r1 = min(r0 + 3, 22), c1 = min(c0 + 3, 22);   // ceil_mode edge
        float mx = -1e30f;
        for (int r = r0; r < r1; ++r)
            for (int c = c0; c < c1; ++c) {
                float acc = 0.f;
                #pragma unroll
                for (int ci = 0; ci < 3; ++ci)
                    #pragma unroll
                    for (int kr = 0; kr < 3; ++kr)
                        #pragma unroll
                        for (int kc = 0; kc < 3; ++kc)
                            acc = fmaf(U[XQ + ci * 600 + (r + kr) * 25 + (c + kc)],
                                       wk[ci * 9 + kr * 3 + kc], acc);
                mx = fmaxf(mx, acc + bias);
            }
        U[ACT1 + idx] = qrelu(mx, sa1);
    }
    __syncthreads();

    // ---- P3: conv2 in 4 quarters of 12 out-ch + maxpool(3,2) ----
    // volatile: W2q@0 (3024), B2q@3024 (12), C2@3036 [12][9][10] -> ends 4116
    for (int q = 0; q < 4; ++q) {
        for (int i = tid; i < 3024; i += 256) U[i] = wsr[W2V + q * 3024 + i];
        if (tid < 12) U[3024 + tid] = wsr[B2V + q * 12 + tid];
        __syncthreads();
        if (tid < 216) {                    // (ol, r, ch): 12*9*2, 5 cols each
            const int ol = tid / 18, rr = tid % 18, r = rr >> 1, ch = rr & 1;
            const int cs = ch * 4;          // 0..4 / 4..8 (col 4 benignly doubled)
            float acc[5];
            #pragma unroll
            for (int c = 0; c < 5; ++c) acc[c] = 0.f;
            for (int ci = 0; ci < 28; ++ci) {
                float wk[9];
                #pragma unroll
                for (int i = 0; i < 9; ++i) wk[i] = U[ol * 252 + ci * 9 + i];
                float win[9];
                #pragma unroll
                for (int kr = 0; kr < 3; ++kr)
                    #pragma unroll
                    for (int kc = 0; kc < 3; ++kc)
                        win[kr * 3 + kc] = U[ACT1 + ci * 121 + (r + kr) * 11 + (cs + kc)];
                #pragma unroll
                for (int c = 0; c < 5; ++c) {
                    #pragma unroll
                    for (int i = 0; i < 9; ++i) acc[c] = fmaf(win[i], wk[i], acc[c]);
                    if (c < 4) {
                        #pragma unroll
                        for (int kr = 0; kr < 3; ++kr) {
                            win[kr * 3 + 0] = win[kr * 3 + 1];
                            win[kr * 3 + 1] = win[kr * 3 + 2];
                            win[kr * 3 + 2] = U[ACT1 + ci * 121 + (r + kr) * 11 + (cs + c + 3)];
                        }
                    }
                }
            }
            const float bias = U[3024 + ol];
            #pragma unroll
            for (int c = 0; c < 5; ++c)
                U[3036 + ol * 90 + r * 10 + (cs + c)] = acc[c] + bias;
        }
        __syncthreads();
        if (tid < 192) {                    // 12*16 pooled
            const int ol = tid / 16, ph = (tid % 16) / 4, pw = tid % 4;
            float mx = -1e30f;
            #pragma unroll
            for (int r = 0; r < 3; ++r)
                #pragma unroll
                for (int c = 0; c < 3; ++c)
                    mx = fmaxf(mx, U[3036 + ol * 90 + (2 * ph + r) * 10 + (2 * pw + c)]);
            U[ACT2 + (q * 12 + ol) * 16 + (tid % 16)] = qrelu(mx, sa2);
        }
        __syncthreads();
    }

    // ---- P4: conv3 in 2 halves of 32 out-ch ----
    // volatile: W3h@0 (6144), B3h@6144 (32)
    for (int hh = 0; hh < 2; ++hh) {
        for (int i = tid; i < 6144; i += 256) U[i] = wsr[W3V + hh * 6144 + i];
        if (tid < 32) U[6144 + tid] = wsr[B3V + hh * 32 + tid];
        __syncthreads();
        for (int idx = tid; idx < 288; idx += 256) {    // 32*3*3
            const int ol = idx / 9, hq = (idx % 9) / 3, wq_ = idx % 3;
            float acc = 0.f;
            for (int ci = 0; ci < 48; ++ci) {
                const int xb = ACT2 + ci * 16, wb = ol * 192 + ci * 4;
                acc = fmaf(U[xb + hq * 4 + wq_],           U[wb + 0], acc);
                acc = fmaf(U[xb + hq * 4 + wq_ + 1],       U[wb + 1], acc);
                acc = fmaf(U[xb + (hq + 1) * 4 + wq_],     U[wb + 2], acc);
                acc = fmaf(U[xb + (hq + 1) * 4 + wq_ + 1], U[wb + 3], acc);
            }
            acc += U[6144 + ol];
            U[ACT3 + (hh * 32 + ol) * 9 + hq * 3 + wq_] = qrelu(acc, sa3);
        }
        __syncthreads();
    }

    // ---- P5: fc1 (576->128), weights [k][o] from ws, coalesced ----
    {
        const int o = tid & 127, half = tid >> 7;
        const float* fw = wsr + FW1V;
        float acc = 0.f;
        const int k0 = half * 288;
        for (int k = k0; k < k0 + 288; ++k)
            acc = fmaf(U[ACT3 + k], fw[k * 128 + o], acc);
        U[tid] = acc;                       // partial@0 (W3 staging dead)
    }
    __syncthreads();
    if (tid < 128) {
        const float acc = U[tid] + U[tid + 128] + wsr[FB1V + tid];
        U[256 + tid] = qrelu(acc, sa4);     // A4@256
    }
    __syncthreads();

    // ---- P6: heads + final signed quant ----
    if (tid < 96) {                         // PART@384
        const int d = tid >> 4, g = tid & 15;
        const float* hw = (d < 4) ? (wsr + BWV + d * 128) : (wsr + CWV + (d - 4) * 128);
        float p = 0.f;
        #pragma unroll
        for (int k = 0; k < 8; ++k)
            p = fmaf(U[256 + g * 8 + k], hw[g * 8 + k], p);
        U[384 + d * 16 + g] = p;
    }
    __syncthreads();
    if (tid < 6) {
        float acc = (tid < 4) ? wsr[BBV + tid] : wsr[CBV + (tid - 4)];
        for (int g = 0; g < 16; ++g) acc += U[384 + tid * 16 + g];
        if (tid < 4)
            outp[(size_t)b * 4 + tid] = fminf(fmaxf(rintf(acc / sab), -8.f), 7.f) * sab;
        else
            outp[16384 + (size_t)b * 2 + (tid - 4)] =
                fminf(fmaxf(rintf(acc / sac), -8.f), 7.f) * sac;
    }
}

// ================= fallback: R7 self-contained kernel (proven) =================
__global__ __launch_bounds__(256) void k_net_fb(
    const void* __restrict__ x,
    const void* __restrict__ w1,  const void* __restrict__ b1,
    const void* __restrict__ w2,  const void* __restrict__ b2,
    const void* __restrict__ w3,  const void* __restrict__ b3,
    const void* __restrict__ fw1, const void* __restrict__ fb1,
    const void* __restrict__ bw,  const void* __restrict__ bb,
    const void* __restrict__ cw,  const void* __restrict__ cb,
    const void* __restrict__ s0p, const void* __restrict__ s1p,
    const void* __restrict__ s2p, const void* __restrict__ s3p,
    const void* __restrict__ s4p, const void* __restrict__ s5p,
    const void* __restrict__ s6p,
    float* __restrict__ outp)
{
    __shared__ float U[16000];
    __shared__ float swsh[8];
    __shared__ float sash[8];
    const int tid = threadIdx.x;
    const int b   = blockIdx.x;
    constexpr int RED = 0, XQ = 0, W1Q = 1728, B1Q = 2484, C1 = 2512;
    constexpr int ACT1 = 9288, WB = 0, C2 = 12676, ACT2 = 14620, ACT3 = 15388;
    constexpr int A4 = 0, PART = 128;

    if (tid == 0) {
        const unsigned short* hb = (const unsigned short*)w1;
        int zeros = 0, sane = 0;
        for (int i = 0; i < 64; ++i) {
            unsigned short u = hb[2 * i];
            float v = __uint_as_float(((unsigned int)u) << 16);
            float a = fabsf(v);
            if (a == 0.f) zeros++;
            else if (a > 1e-8f && a < 1e4f) sane++;
        }
        swsh[7] = (zeros < 40 && sane >= 40) ? 1.f : 0.f;
        const void* sp[7] = { s0p, s1p, s2p, s3p, s4p, s5p, s6p };
        for (int j = 0; j < 7; ++j) {
            float v = *(const float*)sp[j];
            float a = fabsf(v);
            if (!(a > 1e-6f && a < 1e6f)) {
                double d = *(const double*)sp[j];
                double ad = fabs(d);
                if (ad > 1e-6 && ad < 1e6) v = (float)d;
                else {
                    unsigned short u = *(const unsigned short*)sp[j];
                    v = __uint_as_float(((unsigned int)u) << 16);
                }
            }
            sash[j] = v;
        }
    }
    __syncthreads();
    const int isbf = swsh[7] > 0.5f;
    {
        const void* wp[6] = { w1, w2, w3, fw1, bw, cw };
        const int   wn[6] = { 756, 12096, 12288, 73728, 512, 256 };
        for (int j = 0; j < 6; ++j) {
            float m = 0.f;
            for (int i = tid; i < wn[j]; i += 256)
                m = fmaxf(m, fabsf(loadT(wp[j], i, isbf)));
            U[RED + tid] = m; __syncthreads();
            for (int o = 128; o > 0; o >>= 1) {
                if (tid < o) U[RED + tid] = fmaxf(U[RED + tid], U[RED + tid + o]);
                __syncthreads();
            }
            if (tid == 0) swsh[j] = U[RED] / 7.0f;
            __syncthreads();
        }
    }
    const float sa0 = sash[0], sa1 = sash[1], sa2 = sash[2], sa3 = sash[3];
    const float sa4 = sash[4], sab = sash[5], sac = sash[6];
    const float sw1s = swsh[0], sw2s = swsh[1], sw3s = swsh[2];
    const float sw4s = swsh[3], swbs = swsh[4], swcs = swsh[5];

    for (int i = tid; i < 1728; i += 256) {
        float v = loadT(x, (size_t)b * 1728 + i, isbf);
        U[XQ + i] = fminf(fmaxf(rintf(v / sa0), -8.f), 7.f) * sa0;
    }
    for (int i = tid; i < 756; i += 256) U[W1Q + i] = quantw(loadT(w1, i, isbf), sw1s);
    {
        const float den = sa0 * sw1s;
        for (int i = tid; i < 28; i += 256) U[B1Q + i] = qbias(loadT(b1, i, isbf), den);
    }
    __syncthreads();

    for (int g = 0; g < 2; ++g) {
        const int obase = g * 14;
        for (int idx = tid; idx < 308; idx += 256) {
            const int ol = idx / 22, r = idx % 22, o = obase + ol;
            for (int c = 0; c < 22; ++c) {
                float acc = 0.f;
                #pragma unroll
                for (int ci = 0; ci < 3; ++ci)
                    #pragma unroll
                    for (int kr = 0; kr < 3; ++kr)
                        #pragma unroll
                        for (int kc = 0; kc < 3; ++kc)
                            acc = fmaf(U[XQ + ci * 576 + (r + kr) * 24 + (c + kc)],
                                       U[W1Q + o * 27 + ci * 9 + kr * 3 + kc], acc);
                U[C1 + ol * 484 + r * 22 + c] = acc + U[B1Q + o];
            }
        }
        __syncthreads();
        for (int i = tid; i < 1694; i += 256) {
            const int ol = i / 121, rem = i % 121, ph = rem / 11, pw = rem % 11;
            const int r0 = 2 * ph, c0 = 2 * pw;
            const int r1 = min(r0 + 3, 22), c1 = min(c0 + 3, 22);
            float mx = -1e30f;
            for (int r = r0; r < r1; ++r)
                for (int c = c0; c < c1; ++c)
                    mx = fmaxf(mx, U[C1 + ol * 484 + r * 22 + c]);
            U[ACT1 + (obase + ol) * 121 + rem] = qrelu(mx, sa1);
        }
        __syncthreads();
    }

    for (int h = 0; h < 2; ++h) {
        const int obase = h * 24;
        for (int i = tid; i < 6048; i += 256)
            U[WB + i] = quantw(loadT(w2, (size_t)h * 6048 + i, isbf), sw2s);
        {
            const float den = sa1 * sw2s;
            for (int i = tid; i < 24; i += 256)
                U[WB + 6048 + i] = qbias(loadT(b2, obase + i, isbf), den);
        }
        __syncthreads();
        for (int idx = tid; idx < 216; idx += 256) {
            const int ol = idx / 9, r = idx % 9;
            for (int c = 0; c < 9; ++c) {
                float acc = 0.f;
                for (int ci = 0; ci < 28; ++ci)
                    #pragma unroll
                    for (int kr = 0; kr < 3; ++kr)
                        #pragma unroll
                        for (int kc = 0; kc < 3; ++kc)
                            acc = fmaf(U[ACT1 + ci * 121 + (r + kr) * 11 + (c + kc)],
                                       U[WB + ol * 252 + ci * 9 + kr * 3 + kc], acc);
                U[C2 + ol * 81 + r * 9 + c] = acc + U[WB + 6048 + ol];
            }
        }
        __syncthreads();
        for (int i = tid; i < 384; i += 256) {
            const int ol = i / 16, ph = (i % 16) / 4, pw = i % 4;
            float mx = -1e30f;
            #pragma unroll
            for (int r = 0; r < 3; ++r)
                #pragma unroll
                for (int c = 0; c < 3; ++c)
                    mx = fmaxf(mx, U[C2 + ol * 81 + (2 * ph + r) * 9 + (2 * pw + c)]);
            U[ACT2 + (obase + ol) * 16 + (i % 16)] = qrelu(mx, sa2);
        }
        __syncthreads();
    }

    for (int h = 0; h < 2; ++h) {
        const int obase = h * 32;
        for (int i = tid; i < 6144; i += 256)
            U[WB + i] = quantw(loadT(w3, (size_t)h * 6144 + i, isbf), sw3s);
        {
            const float den = sa2 * sw3s;
            for (int i = tid; i < 32; i += 256)
                U[WB + 6144 + i] = qbias(loadT(b3, obase + i, isbf), den);
        }
        __syncthreads();
        for (int idx = tid; idx < 288; idx += 256) {
            const int ol = idx / 9, hh = (idx % 9) / 3, ww = idx % 3;
            float acc = 0.f;
            for (int ci = 0; ci < 48; ++ci) {
                const int xb2 = ACT2 + ci * 16;
                const int wb2 = WB + ol * 192 + ci * 4;
                acc = fmaf(U[xb2 + hh * 4 + ww],           U[wb2 + 0], acc);
                acc = fmaf(U[xb2 + hh * 4 + ww + 1],       U[wb2 + 1], acc);
                acc = fmaf(U[xb2 + (hh + 1) * 4 + ww],     U[wb2 + 2], acc);
                acc = fmaf(U[xb2 + (hh + 1) * 4 + ww + 1], U[wb2 + 3], acc);
            }
            acc += U[WB + 6144 + ol];
            U[ACT3 + (obase + ol) * 9 + hh * 3 + ww] = qrelu(acc, sa3);
        }
        __syncthreads();
    }

    {
        const int wave = tid >> 6, lane = tid & 63;
        const float den = sa3 * sw4s;
        for (int oo = 0; oo < 32; ++oo) {
            const int o = wave * 32 + oo;
            float acc = 0.f;
            #pragma unroll
            for (int j = 0; j < 9; ++j) {
                const int f = lane + 64 * j;
                const int c = f / 9, fw = (f % 9) / 3, fh = f % 3;
                const float av = U[ACT3 + c * 9 + fh * 3 + fw];
                const float wv = quantw(loadT(fw1, (size_t)o * 576 + f, isbf), sw4s);
                acc = fmaf(av, wv, acc);
            }
            #pragma unroll
            for (int off = 32; off > 0; off >>= 1)
                acc += __shfl_down(acc, off);
            if (lane == 0) {
                acc += qbias(loadT(fb1, o, isbf), den);
                U[A4 + o] = qrelu(acc, sa4);
            }
        }
    }
    __syncthreads();

    if (tid < 96) {
        const int d = tid >> 4, g = tid & 15;
        const void* hw = (d < 4) ? bw : cw;
        const int row = (d < 4) ? d : d - 4;
        const float swh = (d < 4) ? swbs : swcs;
        float p = 0.f;
        #pragma unroll
        for (int k = 0; k < 8; ++k) {
            const int kk = g * 8 + k;
            p = fmaf(U[A4 + kk], quantw(loadT(hw, row * 128 + kk, isbf), swh), p);
        }
        U[PART + d * 16 + g] = p;
    }
    __syncthreads();
    if (tid < 6) {
        const int d = tid;
        float acc;
        if (d < 4) acc = qbias(loadT(bb, d, isbf), sa4 * swbs);
        else       acc = qbias(loadT(cb, d - 4, isbf), sa4 * swcs);
        for (int g = 0; g < 16; ++g) acc += U[PART + d * 16 + g];
        if (d < 4) outp[(size_t)b * 4 + d] = fminf(fmaxf(rintf(acc / sab), -8.f), 7.f) * sab;
        else outp[16384 + (size_t)b * 2 + (d - 4)] = fminf(fmaxf(rintf(acc / sac), -8.f), 7.f) * sac;
    }
}

extern "C" void kernel_launch(void* const* d_in, const int* in_sizes, int n_in,
                              void* d_out, int out_size, void* d_ws, size_t ws_size,
                              hipStream_t stream)
{
    float* out = (float*)d_out;
    const int expect[20] = { 7077888, 756, 28, 12096, 48, 12288, 64, 73728, 128,
                             512, 4, 256, 2, 1, 1, 1, 1, 1, 1, 1 };
    if (n_in < 20) { k_beacon<<<1, 64, 0, stream>>>(out, 9000.f); return; }
    for (int i = 0; i < 20; ++i)
        if (in_sizes[i] != expect[i]) {
            k_beacon<<<1, 64, 0, stream>>>(out, 2000.f + 10.f * i);
            return;
        }

    if (ws_size >= (size_t)100000 * sizeof(float)) {
        float* ws = (float*)d_ws;
        k_prep<<<6, 256, 0, stream>>>(
            d_in[1], d_in[2], d_in[3], d_in[4], d_in[5], d_in[6],
            d_in[7], d_in[8], d_in[9], d_in[10], d_in[11], d_in[12],
            d_in[13], d_in[14], d_in[15], d_in[16], d_in[17], d_in[18], d_in[19],
            ws);
        k_net<<<4096, 256, 0, stream>>>(d_in[0], ws, out);
    } else {
        k_net_fb<<<4096, 256, 0, stream>>>(
            d_in[0], d_in[1], d_in[2], d_in[3], d_in[4], d_in[5], d_in[6],
            d_in[7], d_in[8], d_in[9], d_in[10], d_in[11], d_in[12],
            d_in[13], d_in[14], d_in[15], d_in[16], d_in[17], d_in[18], d_in[19],
            out);
    }
}

// Round 9
// 579.775 us; speedup vs baseline: 4.0598x; 1.8676x over previous
//
#include <hip/hip_runtime.h>
#include <hip/hip_bf16.h>
#include <math.h>

// ================= shared helpers =================
__device__ __forceinline__ float loadT(const void* p, size_t i, int isbf) {
    if (isbf) return __bfloat162float(((const __hip_bfloat16*)p)[i]);
    return ((const float*)p)[i];
}
__device__ __forceinline__ float quantw(float v, float s) {      // weight: [-7,7]
    return fminf(fmaxf(rintf(v / s), -7.f), 7.f) * s;
}
__device__ __forceinline__ float qbias(float v, float den) {     // Int32Bias
    return rintf(v / den) * den;
}
__device__ __forceinline__ float qrelu(float v, float s) {       // [0,15]
    return fminf(fmaxf(rintf(fmaxf(v, 0.f) / s), 0.f), 15.f) * s;
}

__global__ void k_beacon(float* out, float code) {
    if (threadIdx.x == 0 && blockIdx.x == 0) out[0] = code;
}

// ================= ws layout (floats) =================
// [0..6] activation scales sa0..sa4, sab, sac ; [15] isbf flag
static constexpr int W1V  = 16;     // 756
static constexpr int B1V  = 772;    // 28
static constexpr int W2V  = 800;    // 12096
static constexpr int B2V  = 12896;  // 48
static constexpr int W3V  = 12944;  // 12288
static constexpr int B3V  = 25232;  // 64
static constexpr int FW1V = 25296;  // 73728  [k][o], flatten-folded
static constexpr int FB1V = 99024;  // 128
static constexpr int BWV  = 99152;  // 512
static constexpr int BBV  = 99664;  // 4
static constexpr int CWV  = 99668;  // 256
static constexpr int CBV  = 99924;  // 2  -> end 99926 floats (≈400 KB)

// ================= prep: quantize all weights/biases once =================
__global__ __launch_bounds__(256) void k_prep(
    const void* w1, const void* b1, const void* w2, const void* b2,
    const void* w3, const void* b3, const void* fw1, const void* fb1,
    const void* bw, const void* bb, const void* cw, const void* cb,
    const void* s0p, const void* s1p, const void* s2p, const void* s3p,
    const void* s4p, const void* s5p, const void* s6p,
    float* __restrict__ ws)
{
    __shared__ float red[256];
    __shared__ float sh[2];            // [0]=isbf, [1]=pre-scale for this block
    const int tid = threadIdx.x, blk = blockIdx.x;
    if (tid == 0) {
        const unsigned short* hb = (const unsigned short*)w1;
        int zeros = 0, sane = 0;
        for (int i = 0; i < 64; ++i) {
            unsigned short u = hb[2 * i];
            float v = __uint_as_float(((unsigned int)u) << 16);
            float a = fabsf(v);
            if (a == 0.f) zeros++;
            else if (a > 1e-8f && a < 1e4f) sane++;
        }
        const float isbf = (zeros < 40 && sane >= 40) ? 1.f : 0.f;
        sh[0] = isbf;
        const void* sp[7] = { s0p, s1p, s2p, s3p, s4p, s5p, s6p };
        float sa[7];
        for (int j = 0; j < 7; ++j) {
            float v = *(const float*)sp[j];
            float a = fabsf(v);
            if (!(a > 1e-6f && a < 1e6f)) {
                double d = *(const double*)sp[j];
                double ad = fabs(d);
                if (ad > 1e-6 && ad < 1e6) v = (float)d;
                else {
                    unsigned short u = *(const unsigned short*)sp[j];
                    v = __uint_as_float(((unsigned int)u) << 16);
                }
            }
            sa[j] = v;
        }
        if (blk == 0) {
            for (int j = 0; j < 7; ++j) ws[j] = sa[j];
            ws[15] = isbf;
        }
        const int preidx[6] = { 0, 1, 2, 3, 4, 4 };
        sh[1] = sa[preidx[blk]];
    }
    __syncthreads();
    const int isbf = sh[0] > 0.5f;
    const float pre = sh[1];

    const void* wp[6] = { w1, w2, w3, fw1, bw, cw };
    const void* bp[6] = { b1, b2, b3, fb1, bb, cb };
    const int   wn[6] = { 756, 12096, 12288, 73728, 512, 256 };
    const int   bn[6] = { 28, 48, 64, 128, 4, 2 };
    const int   wo[6] = { W1V, W2V, W3V, FW1V, BWV, CWV };
    const int   bo[6] = { B1V, B2V, B3V, FB1V, BBV, CBV };
    const void* w = wp[blk]; const void* b = bp[blk];
    const int nw = wn[blk], nb = bn[blk], qwo = wo[blk], qbo = bo[blk];

    float m = 0.f;
    for (int i = tid; i < nw; i += 256) m = fmaxf(m, fabsf(loadT(w, i, isbf)));
    red[tid] = m; __syncthreads();
    for (int o = 128; o > 0; o >>= 1) {
        if (tid < o) red[tid] = fmaxf(red[tid], red[tid + o]);
        __syncthreads();
    }
    const float s = red[0] / 7.0f;                 // max|w|/7
    for (int i = tid; i < nw; i += 256) {
        float q = quantw(loadT(w, i, isbf), s);    // quantized VALUE
        int oi = i;
        if (blk == 3) {
            // transpose to [k][o], folding QuantFlatten's transpose(3,2):
            // ref col f = c*9 + w*3 + h ; act3 flat k = c*9 + h*3 + w
            int o = i / 576, f = i % 576;
            int c = f / 9, fw_ = (f % 9) / 3, fh = f % 3;
            oi = (c * 9 + fh * 3 + fw_) * 128 + o;
        }
        ws[qwo + oi] = q;
    }
    const float den = pre * s;                     // Int32Bias scale
    for (int i = tid; i < nb; i += 256)
        ws[qbo + i] = qbias(loadT(b, i, isbf), den);
}

// ================= main fused per-sample kernel (prep path) =================
// LDS union U[8848] = 35392 B -> 4 blocks/CU.
// persistent: ACT1@4116 [28][11][11], ACT2@7504 [48][4][4], ACT3@8272 [64][3][3]
__global__ __launch_bounds__(256, 4) void k_net(
    const void* __restrict__ x, const float* __restrict__ wsr,
    float* __restrict__ outp)
{
    __shared__ __align__(16) float U[8848];
    const int tid = threadIdx.x, b = blockIdx.x;
    const float sa0 = wsr[0], sa1 = wsr[1], sa2 = wsr[2], sa3 = wsr[3];
    const float sa4 = wsr[4], sab = wsr[5], sac = wsr[6];
    const int isbf = wsr[15] > 0.5f;
    constexpr int XQ = 0, W1 = 1800, B1 = 2556;        // XQ [3][24][25] padded
    constexpr int ACT1 = 4116, ACT2 = 7504, ACT3 = 8272;

    // ---- P1: quantize input + stage conv1 weights ----
    for (int i = tid; i < 1728; i += 256) {
        float v = loadT(x, (size_t)b * 1728 + i, isbf);
        const int ci = i / 576, r = (i % 576) / 24, c = i % 24;
        U[XQ + ci * 600 + r * 25 + c] = fminf(fmaxf(rintf(v / sa0), -8.f), 7.f) * sa0;
    }
    for (int i = tid; i < 756; i += 256) U[W1 + i] = wsr[W1V + i];
    if (tid < 28) U[B1 + tid] = wsr[B1V + tid];
    __syncthreads();

    // ---- P2: conv1 rows + fused maxpool(3,2,ceil), sliding 3x5x3 reg window ----
    // item = (o, ph): thread computes conv rows 2ph..2ph+2 (clipped) across all
    // 22 cols, streaming the 11 pooled outputs. Bank-conflict-free: addr depends
    // on ph via (2ph+ir)*25; 50*ph mod 32 all-distinct over ph=0..10.
    for (int item = tid; item < 308; item += 256) {
        const int o = item / 11, ph = item % 11;
        const int r0 = 2 * ph;
        const bool row2ok = (r0 + 2) < 22;      // conv row r0+2 exists?
        float wk[27];
        #pragma unroll
        for (int i = 0; i < 27; ++i) wk[i] = U[W1 + o * 27 + i];
        const float bias = U[B1 + o];
        // window w5[ci][ir][j]: input rows r0+ir (ir<5, guarded), cols c+j
        float w5[45];
        #pragma unroll
        for (int ci = 0; ci < 3; ++ci)
            #pragma unroll
            for (int ir = 0; ir < 5; ++ir)
                #pragma unroll
                for (int j = 0; j < 2; ++j)
                    w5[ci * 15 + ir * 3 + j] =
                        (r0 + ir < 24) ? U[XQ + ci * 600 + (r0 + ir) * 25 + j] : 0.f;
        float accP = -1e30f, accC = -1e30f;
        for (int c = 0; c < 22; ++c) {
            #pragma unroll
            for (int ci = 0; ci < 3; ++ci)
                #pragma unroll
                for (int ir = 0; ir < 5; ++ir)
                    w5[ci * 15 + ir * 3 + 2] =
                        (r0 + ir < 24) ? U[XQ + ci * 600 + (r0 + ir) * 25 + (c + 2)] : 0.f;
            float a0 = 0.f, a1 = 0.f, a2 = 0.f;    // conv rows r0, r0+1, r0+2
            #pragma unroll
            for (int ci = 0; ci < 3; ++ci)
                #pragma unroll
                for (int kr = 0; kr < 3; ++kr)
                    #pragma unroll
                    for (int kc = 0; kc < 3; ++kc) {
                        const float w = wk[ci * 9 + kr * 3 + kc];
                        a0 = fmaf(w5[ci * 15 + (kr + 0) * 3 + kc], w, a0);
                        a1 = fmaf(w5[ci * 15 + (kr + 1) * 3 + kc], w, a1);
                        a2 = fmaf(w5[ci * 15 + (kr + 2) * 3 + kc], w, a2);
                    }
            float cm = fmaxf(a0, a1);
            cm = row2ok ? fmaxf(cm, a2) : cm;
            if ((c & 1) == 0) {
                if (c >= 2)
                    U[ACT1 + o * 121 + ph * 11 + (c / 2 - 1)] =
                        qrelu(fmaxf(accP, cm) + bias, sa1);
                accC = cm;
            } else {
                accC = fmaxf(accC, cm);
                accP = accC;
            }
            #pragma unroll
            for (int ci = 0; ci < 3; ++ci)
                #pragma unroll
                for (int ir = 0; ir < 5; ++ir) {
                    w5[ci * 15 + ir * 3 + 0] = w5[ci * 15 + ir * 3 + 1];
                    w5[ci * 15 + ir * 3 + 1] = w5[ci * 15 + ir * 3 + 2];
                }
        }
        U[ACT1 + o * 121 + ph * 11 + 10] = qrelu(accP + bias, sa1);  // ceil edge
    }
    __syncthreads();

    // ---- P3: conv2 in 4 quarters of 12 out-ch + maxpool(3,2) ----
    // volatile: W2q@0 (3024), B2q@3024 (12), C2@3036 [12][9][10] -> ends 4116
    for (int q = 0; q < 4; ++q) {
        {
            const float4* w4 = (const float4*)(wsr + W2V + q * 3024);
            float4* u4 = (float4*)U;
            for (int i = tid; i < 756; i += 256) u4[i] = w4[i];
        }
        if (tid < 12) U[3024 + tid] = wsr[B2V + q * 12 + tid];
        __syncthreads();
        if (tid < 216) {                    // (ol, r, ch): 12*9*2, 5 cols each
            const int ol = tid / 18, rr = tid % 18, r = rr >> 1, ch = rr & 1;
            const int cs = ch * 4;          // 0..4 / 4..8 (col 4 benignly doubled)
            float acc[5];
            #pragma unroll
            for (int c = 0; c < 5; ++c) acc[c] = 0.f;
            for (int ci = 0; ci < 28; ++ci) {
                float wk[9];
                #pragma unroll
                for (int i = 0; i < 9; ++i) wk[i] = U[ol * 252 + ci * 9 + i];
                float win[9];
                #pragma unroll
                for (int kr = 0; kr < 3; ++kr)
                    #pragma unroll
                    for (int kc = 0; kc < 3; ++kc)
                        win[kr * 3 + kc] = U[ACT1 + ci * 121 + (r + kr) * 11 + (cs + kc)];
                #pragma unroll
                for (int c = 0; c < 5; ++c) {
                    #pragma unroll
                    for (int i = 0; i < 9; ++i) acc[c] = fmaf(win[i], wk[i], acc[c]);
                    if (c < 4) {
                        #pragma unroll
                        for (int kr = 0; kr < 3; ++kr) {
                            win[kr * 3 + 0] = win[kr * 3 + 1];
                            win[kr * 3 + 1] = win[kr * 3 + 2];
                            win[kr * 3 + 2] = U[ACT1 + ci * 121 + (r + kr) * 11 + (cs + c + 3)];
                        }
                    }
                }
            }
            const float bias = U[3024 + ol];
            #pragma unroll
            for (int c = 0; c < 5; ++c)
                U[3036 + ol * 90 + r * 10 + (cs + c)] = acc[c] + bias;
        }
        __syncthreads();
        if (tid < 192) {                    // 12*16 pooled
            const int ol = tid / 16, ph = (tid % 16) / 4, pw = tid % 4;
            float mx = -1e30f;
            #pragma unroll
            for (int r = 0; r < 3; ++r)
                #pragma unroll
                for (int c = 0; c < 3; ++c)
                    mx = fmaxf(mx, U[3036 + ol * 90 + (2 * ph + r) * 10 + (2 * pw + c)]);
            U[ACT2 + (q * 12 + ol) * 16 + (tid % 16)] = qrelu(mx, sa2);
        }
        __syncthreads();
    }

    // ---- P4: conv3 in 2 halves of 32 out-ch ----
    // volatile: W3h@0 (6144), B3h@6144 (32)  (overlaps dead ACT1 tail region ok)
    for (int hh = 0; hh < 2; ++hh) {
        {
            const float4* w4 = (const float4*)(wsr + W3V + hh * 6144);
            float4* u4 = (float4*)U;
            for (int i = tid; i < 1536; i += 256) u4[i] = w4[i];
        }
        if (tid < 32) U[6144 + tid] = wsr[B3V + hh * 32 + tid];
        __syncthreads();
        for (int idx = tid; idx < 288; idx += 256) {    // 32*3*3
            const int ol = idx / 9, hq = (idx % 9) / 3, wq_ = idx % 3;
            float acc = 0.f;
            for (int ci = 0; ci < 48; ++ci) {
                const int xb = ACT2 + ci * 16, wb = ol * 192 + ci * 4;
                acc = fmaf(U[xb + hq * 4 + wq_],           U[wb + 0], acc);
                acc = fmaf(U[xb + hq * 4 + wq_ + 1],       U[wb + 1], acc);
                acc = fmaf(U[xb + (hq + 1) * 4 + wq_],     U[wb + 2], acc);
                acc = fmaf(U[xb + (hq + 1) * 4 + wq_ + 1], U[wb + 3], acc);
            }
            acc += U[6144 + ol];
            U[ACT3 + (hh * 32 + ol) * 9 + hq * 3 + wq_] = qrelu(acc, sa3);
        }
        __syncthreads();
    }

    // ---- P5: fc1 (576->128), weights [k][o] from ws, coalesced ----
    {
        const int o = tid & 127, half = tid >> 7;
        const float* fw = wsr + FW1V;
        float acc = 0.f;
        const int k0 = half * 288;
        for (int k = k0; k < k0 + 288; ++k)
            acc = fmaf(U[ACT3 + k], fw[k * 128 + o], acc);
        U[tid] = acc;                       // partial@0 (volatile region dead)
    }
    __syncthreads();
    if (tid < 128) {
        const float acc = U[tid] + U[tid + 128] + wsr[FB1V + tid];
        U[256 + tid] = qrelu(acc, sa4);     // A4@256
    }
    __syncthreads();

    // ---- P6: heads + final signed quant ----
    if (tid < 96) {                         // PART@384
        const int d = tid >> 4, g = tid & 15;
        const float* hw = (d < 4) ? (wsr + BWV + d * 128) : (wsr + CWV + (d - 4) * 128);
        float p = 0.f;
        #pragma unroll
        for (int k = 0; k < 8; ++k)
            p = fmaf(U[256 + g * 8 + k], hw[g * 8 + k], p);
        U[384 + d * 16 + g] = p;
    }
    __syncthreads();
    if (tid < 6) {
        float acc = (tid < 4) ? wsr[BBV + tid] : wsr[CBV + (tid - 4)];
        for (int g = 0; g < 16; ++g) acc += U[384 + tid * 16 + g];
        if (tid < 4)
            outp[(size_t)b * 4 + tid] = fminf(fmaxf(rintf(acc / sab), -8.f), 7.f) * sab;
        else
            outp[16384 + (size_t)b * 2 + (tid - 4)] =
                fminf(fmaxf(rintf(acc / sac), -8.f), 7.f) * sac;
    }
}

// ================= fallback: R7 self-contained kernel (proven) =================
__global__ __launch_bounds__(256) void k_net_fb(
    const void* __restrict__ x,
    const void* __restrict__ w1,  const void* __restrict__ b1,
    const void* __restrict__ w2,  const void* __restrict__ b2,
    const void* __restrict__ w3,  const void* __restrict__ b3,
    const void* __restrict__ fw1, const void* __restrict__ fb1,
    const void* __restrict__ bw,  const void* __restrict__ bb,
    const void* __restrict__ cw,  const void* __restrict__ cb,
    const void* __restrict__ s0p, const void* __restrict__ s1p,
    const void* __restrict__ s2p, const void* __restrict__ s3p,
    const void* __restrict__ s4p, const void* __restrict__ s5p,
    const void* __restrict__ s6p,
    float* __restrict__ outp)
{
    __shared__ float U[16000];
    __shared__ float swsh[8];
    __shared__ float sash[8];
    const int tid = threadIdx.x;
    const int b   = blockIdx.x;
    constexpr int RED = 0, XQ = 0, W1Q = 1728, B1Q = 2484, C1 = 2512;
    constexpr int ACT1 = 9288, WB = 0, C2 = 12676, ACT2 = 14620, ACT3 = 15388;
    constexpr int A4 = 0, PART = 128;

    if (tid == 0) {
        const unsigned short* hb = (const unsigned short*)w1;
        int zeros = 0, sane = 0;
        for (int i = 0; i < 64; ++i) {
            unsigned short u = hb[2 * i];
            float v = __uint_as_float(((unsigned int)u) << 16);
            float a = fabsf(v);
            if (a == 0.f) zeros++;
            else if (a > 1e-8f && a < 1e4f) sane++;
        }
        swsh[7] = (zeros < 40 && sane >= 40) ? 1.f : 0.f;
        const void* sp[7] = { s0p, s1p, s2p, s3p, s4p, s5p, s6p };
        for (int j = 0; j < 7; ++j) {
            float v = *(const float*)sp[j];
            float a = fabsf(v);
            if (!(a > 1e-6f && a < 1e6f)) {
                double d = *(const double*)sp[j];
                double ad = fabs(d);
                if (ad > 1e-6 && ad < 1e6) v = (float)d;
                else {
                    unsigned short u = *(const unsigned short*)sp[j];
                    v = __uint_as_float(((unsigned int)u) << 16);
                }
            }
            sash[j] = v;
        }
    }
    __syncthreads();
    const int isbf = swsh[7] > 0.5f;
    {
        const void* wp[6] = { w1, w2, w3, fw1, bw, cw };
        const int   wn[6] = { 756, 12096, 12288, 73728, 512, 256 };
        for (int j = 0; j < 6; ++j) {
            float m = 0.f;
            for (int i = tid; i < wn[j]; i += 256)
                m = fmaxf(m, fabsf(loadT(wp[j], i, isbf)));
            U[RED + tid] = m; __syncthreads();
            for (int o = 128; o > 0; o >>= 1) {
                if (tid < o) U[RED + tid] = fmaxf(U[RED + tid], U[RED + tid + o]);
                __syncthreads();
            }
            if (tid == 0) swsh[j] = U[RED] / 7.0f;
            __syncthreads();
        }
    }
    const float sa0 = sash[0], sa1 = sash[1], sa2 = sash[2], sa3 = sash[3];
    const float sa4 = sash[4], sab = sash[5], sac = sash[6];
    const float sw1s = swsh[0], sw2s = swsh[1], sw3s = swsh[2];
    const float sw4s = swsh[3], swbs = swsh[4], swcs = swsh[5];

    for (int i = tid; i < 1728; i += 256) {
        float v = loadT(x, (size_t)b * 1728 + i, isbf);
        U[XQ + i] = fminf(fmaxf(rintf(v / sa0), -8.f), 7.f) * sa0;
    }
    for (int i = tid; i < 756; i += 256) U[W1Q + i] = quantw(loadT(w1, i, isbf), sw1s);
    {
        const float den = sa0 * sw1s;
        for (int i = tid; i < 28; i += 256) U[B1Q + i] = qbias(loadT(b1, i, isbf), den);
    }
    __syncthreads();

    for (int g = 0; g < 2; ++g) {
        const int obase = g * 14;
        for (int idx = tid; idx < 308; idx += 256) {
            const int ol = idx / 22, r = idx % 22, o = obase + ol;
            for (int c = 0; c < 22; ++c) {
                float acc = 0.f;
                #pragma unroll
                for (int ci = 0; ci < 3; ++ci)
                    #pragma unroll
                    for (int kr = 0; kr < 3; ++kr)
                        #pragma unroll
                        for (int kc = 0; kc < 3; ++kc)
                            acc = fmaf(U[XQ + ci * 576 + (r + kr) * 24 + (c + kc)],
                                       U[W1Q + o * 27 + ci * 9 + kr * 3 + kc], acc);
                U[C1 + ol * 484 + r * 22 + c] = acc + U[B1Q + o];
            }
        }
        __syncthreads();
        for (int i = tid; i < 1694; i += 256) {
            const int ol = i / 121, rem = i % 121, ph = rem / 11, pw = rem % 11;
            const int r0 = 2 * ph, c0 = 2 * pw;
            const int r1 = min(r0 + 3, 22), c1 = min(c0 + 3, 22);
            float mx = -1e30f;
            for (int r = r0; r < r1; ++r)
                for (int c = c0; c < c1; ++c)
                    mx = fmaxf(mx, U[C1 + ol * 484 + r * 22 + c]);
            U[ACT1 + (obase + ol) * 121 + rem] = qrelu(mx, sa1);
        }
        __syncthreads();
    }

    for (int h = 0; h < 2; ++h) {
        const int obase = h * 24;
        for (int i = tid; i < 6048; i += 256)
            U[WB + i] = quantw(loadT(w2, (size_t)h * 6048 + i, isbf), sw2s);
        {
            const float den = sa1 * sw2s;
            for (int i = tid; i < 24; i += 256)
                U[WB + 6048 + i] = qbias(loadT(b2, obase + i, isbf), den);
        }
        __syncthreads();
        for (int idx = tid; idx < 216; idx += 256) {
            const int ol = idx / 9, r = idx % 9;
            for (int c = 0; c < 9; ++c) {
                float acc = 0.f;
                for (int ci = 0; ci < 28; ++ci)
                    #pragma unroll
                    for (int kr = 0; kr < 3; ++kr)
                        #pragma unroll
                        for (int kc = 0; kc < 3; ++kc)
                            acc = fmaf(U[ACT1 + ci * 121 + (r + kr) * 11 + (c + kc)],
                                       U[WB + ol * 252 + ci * 9 + kr * 3 + kc], acc);
                U[C2 + ol * 81 + r * 9 + c] = acc + U[WB + 6048 + ol];
            }
        }
        __syncthreads();
        for (int i = tid; i < 384; i += 256) {
            const int ol = i / 16, ph = (i % 16) / 4, pw = i % 4;
            float mx = -1e30f;
            #pragma unroll
            for (int r = 0; r < 3; ++r)
                #pragma unroll
                for (int c = 0; c < 3; ++c)
                    mx = fmaxf(mx, U[C2 + ol * 81 + (2 * ph + r) * 9 + (2 * pw + c)]);
            U[ACT2 + (obase + ol) * 16 + (i % 16)] = qrelu(mx, sa2);
        }
        __syncthreads();
    }

    for (int h = 0; h < 2; ++h) {
        const int obase = h * 32;
        for (int i = tid; i < 6144; i += 256)
            U[WB + i] = quantw(loadT(w3, (size_t)h * 6144 + i, isbf), sw3s);
        {
            const float den = sa2 * sw3s;
            for (int i = tid; i < 32; i += 256)
                U[WB + 6144 + i] = qbias(loadT(b3, obase + i, isbf), den);
        }
        __syncthreads();
        for (int idx = tid; idx < 288; idx += 256) {
            const int ol = idx / 9, hh = (idx % 9) / 3, ww = idx % 3;
            float acc = 0.f;
            for (int ci = 0; ci < 48; ++ci) {
                const int xb2 = ACT2 + ci * 16;
                const int wb2 = WB + ol * 192 + ci * 4;
                acc = fmaf(U[xb2 + hh * 4 + ww],           U[wb2 + 0], acc);
                acc = fmaf(U[xb2 + hh * 4 + ww + 1],       U[wb2 + 1], acc);
                acc = fmaf(U[xb2 + (hh + 1) * 4 + ww],     U[wb2 + 2], acc);
                acc = fmaf(U[xb2 + (hh + 1) * 4 + ww + 1], U[wb2 + 3], acc);
            }
            acc += U[WB + 6144 + ol];
            U[ACT3 + (obase + ol) * 9 + hh * 3 + ww] = qrelu(acc, sa3);
        }
        __syncthreads();
    }

    {
        const int wave = tid >> 6, lane = tid & 63;
        const float den = sa3 * sw4s;
        for (int oo = 0; oo < 32; ++oo) {
            const int o = wave * 32 + oo;
            float acc = 0.f;
            #pragma unroll
            for (int j = 0; j < 9; ++j) {
                const int f = lane + 64 * j;
                const int c = f / 9, fw = (f % 9) / 3, fh = f % 3;
                const float av = U[ACT3 + c * 9 + fh * 3 + fw];
                const float wv = quantw(loadT(fw1, (size_t)o * 576 + f, isbf), sw4s);
                acc = fmaf(av, wv, acc);
            }
            #pragma unroll
            for (int off = 32; off > 0; off >>= 1)
                acc += __shfl_down(acc, off);
            if (lane == 0) {
                acc += qbias(loadT(fb1, o, isbf), den);
                U[A4 + o] = qrelu(acc, sa4);
            }
        }
    }
    __syncthreads();

    if (tid < 96) {
        const int d = tid >> 4, g = tid & 15;
        const void* hw = (d < 4) ? bw : cw;
        const int row = (d < 4) ? d : d - 4;
        const float swh = (d < 4) ? swbs : swcs;
        float p = 0.f;
        #pragma unroll
        for (int k = 0; k < 8; ++k) {
            const int kk = g * 8 + k;
            p = fmaf(U[A4 + kk], quantw(loadT(hw, row * 128 + kk, isbf), swh), p);
        }
        U[PART + d * 16 + g] = p;
    }
    __syncthreads();
    if (tid < 6) {
        const int d = tid;
        float acc;
        if (d < 4) acc = qbias(loadT(bb, d, isbf), sa4 * swbs);
        else       acc = qbias(loadT(cb, d - 4, isbf), sa4 * swcs);
        for (int g = 0; g < 16; ++g) acc += U[PART + d * 16 + g];
        if (d < 4) outp[(size_t)b * 4 + d] = fminf(fmaxf(rintf(acc / sab), -8.f), 7.f) * sab;
        else outp[16384 + (size_t)b * 2 + (d - 4)] = fminf(fmaxf(rintf(acc / sac), -8.f), 7.f) * sac;
    }
}

extern "C" void kernel_launch(void* const* d_in, const int* in_sizes, int n_in,
                              void* d_out, int out_size, void* d_ws, size_t ws_size,
                              hipStream_t stream)
{
    float* out = (float*)d_out;
    const int expect[20] = { 7077888, 756, 28, 12096, 48, 12288, 64, 73728, 128,
                             512, 4, 256, 2, 1, 1, 1, 1, 1, 1, 1 };
    if (n_in < 20) { k_beacon<<<1, 64, 0, stream>>>(out, 9000.f); return; }
    for (int i = 0; i < 20; ++i)
        if (in_sizes[i] != expect[i]) {
            k_beacon<<<1, 64, 0, stream>>>(out, 2000.f + 10.f * i);
            return;
        }

    if (ws_size >= (size_t)100000 * sizeof(float)) {
        float* ws = (float*)d_ws;
        k_prep<<<6, 256, 0, stream>>>(
            d_in[1], d_in[2], d_in[3], d_in[4], d_in[5], d_in[6],
            d_in[7], d_in[8], d_in[9], d_in[10], d_in[11], d_in[12],
            d_in[13], d_in[14], d_in[15], d_in[16], d_in[17], d_in[18], d_in[19],
            ws);
        k_net<<<4096, 256, 0, stream>>>(d_in[0], ws, out);
    } else {
        k_net_fb<<<4096, 256, 0, stream>>>(
            d_in[0], d_in[1], d_in[2], d_in[3], d_in[4], d_in[5], d_in[6],
            d_in[7], d_in[8], d_in[9], d_in[10], d_in[11], d_in[12],
            d_in[13], d_in[14], d_in[15], d_in[16], d_in[17], d_in[18], d_in[19],
            out);
    }
}

// Round 10
// 399.295 us; speedup vs baseline: 5.8949x; 1.4520x over previous
//
#include <hip/hip_runtime.h>
#include <hip/hip_bf16.h>
#include <math.h>

typedef __attribute__((ext_vector_type(8))) short bf16x8v;   // 8 bf16 (4 VGPR)
typedef __attribute__((ext_vector_type(4))) float f32x4v;

// ================= shared helpers =================
__device__ __forceinline__ float loadT(const void* p, size_t i, int isbf) {
    if (isbf) return __bfloat162float(((const __hip_bfloat16*)p)[i]);
    return ((const float*)p)[i];
}
__device__ __forceinline__ float quantw(float v, float s) {      // weight VALUE
    return fminf(fmaxf(rintf(v / s), -7.f), 7.f) * s;
}
__device__ __forceinline__ float quantwc(float v, float s) {     // weight CODE
    return fminf(fmaxf(rintf(v / s), -7.f), 7.f);
}
__device__ __forceinline__ float qbias(float v, float den) {     // Int32Bias VALUE
    return rintf(v / den) * den;
}
__device__ __forceinline__ float qrelu(float v, float s) {       // [0,15] VALUE
    return fminf(fmaxf(rintf(fmaxf(v, 0.f) / s), 0.f), 15.f) * s;
}
// code-domain quant-relu: Cint+bias code -> next-layer code
__device__ __forceinline__ float qcode(float Cint, float bcode, float p, float snext) {
    float v = (Cint + bcode) * p;
    return fminf(fmaxf(rintf(fmaxf(v, 0.f) / snext), 0.f), 15.f);
}
__device__ __forceinline__ float bfbits(unsigned u) {            // bf16 bits -> f32
    return __uint_as_float(u << 16);
}

__global__ void k_beacon(float* out, float code) {
    if (threadIdx.x == 0 && blockIdx.x == 0) out[0] = code;
}

// ================= ws layout (floats) =================
// [0..6]=sa0..sa4,sab,sac ; [8..13]=p1,p2,p3,p4,pB,pC ; [15]=isbf
static constexpr int W1C  = 16;     // 756   f32 codes
static constexpr int B1C  = 772;    // 28    f32 codes
static constexpr int B2C  = 800;    // 48
static constexpr int B3C  = 848;    // 64
static constexpr int FB1C = 912;    // 128
static constexpr int BBC  = 1040;   // 4
static constexpr int CBC  = 1044;   // 2
static constexpr int FW1B = 1048;   // 36864 floats = 73728 bf16 codes [k][o]
static constexpr int W2B  = 37912;  // 6144 floats = 12288 bf16 codes [48][256] (k-pad)
static constexpr int W3B  = 44056;  // 6144 floats = 12288 bf16 codes [64][48][2][2]
static constexpr int BWC  = 50200;  // 512  f32 codes
static constexpr int CWC  = 50712;  // 256  f32 codes  -> end 50968 (~204 KB)

// ================= prep =================
__global__ __launch_bounds__(256) void k_prep(
    const void* w1, const void* b1, const void* w2, const void* b2,
    const void* w3, const void* b3, const void* fw1, const void* fb1,
    const void* bw, const void* bb, const void* cw, const void* cb,
    const void* s0p, const void* s1p, const void* s2p, const void* s3p,
    const void* s4p, const void* s5p, const void* s6p,
    float* __restrict__ ws)
{
    __shared__ float red[256];
    __shared__ float sh[2];
    const int tid = threadIdx.x, blk = blockIdx.x;
    if (tid == 0) {
        const unsigned short* hb = (const unsigned short*)w1;
        int zeros = 0, sane = 0;
        for (int i = 0; i < 64; ++i) {
            unsigned short u = hb[2 * i];
            float v = __uint_as_float(((unsigned int)u) << 16);
            float a = fabsf(v);
            if (a == 0.f) zeros++;
            else if (a > 1e-8f && a < 1e4f) sane++;
        }
        const float isbf = (zeros < 40 && sane >= 40) ? 1.f : 0.f;
        sh[0] = isbf;
        const void* sp[7] = { s0p, s1p, s2p, s3p, s4p, s5p, s6p };
        float sa[7];
        for (int j = 0; j < 7; ++j) {
            float v = *(const float*)sp[j];
            float a = fabsf(v);
            if (!(a > 1e-6f && a < 1e6f)) {
                double d = *(const double*)sp[j];
                double ad = fabs(d);
                if (ad > 1e-6 && ad < 1e6) v = (float)d;
                else {
                    unsigned short u = *(const unsigned short*)sp[j];
                    v = __uint_as_float(((unsigned int)u) << 16);
                }
            }
            sa[j] = v;
        }
        if (blk == 0) {
            for (int j = 0; j < 7; ++j) ws[j] = sa[j];
            ws[15] = isbf;
        }
        const int preidx[6] = { 0, 1, 2, 3, 4, 4 };
        sh[1] = sa[preidx[blk]];
    }
    __syncthreads();
    const int isbf = sh[0] > 0.5f;
    const float pre = sh[1];

    const void* wp[6] = { w1, w2, w3, fw1, bw, cw };
    const void* bp[6] = { b1, b2, b3, fb1, bb, cb };
    const int   wn[6] = { 756, 12096, 12288, 73728, 512, 256 };
    const int   bn[6] = { 28, 48, 64, 128, 4, 2 };
    const int   bo[6] = { B1C, B2C, B3C, FB1C, BBC, CBC };
    const void* w = wp[blk]; const void* b = bp[blk];
    const int nw = wn[blk], nb = bn[blk], qbo = bo[blk];

    float m = 0.f;
    for (int i = tid; i < nw; i += 256) m = fmaxf(m, fabsf(loadT(w, i, isbf)));
    red[tid] = m; __syncthreads();
    for (int o = 128; o > 0; o >>= 1) {
        if (tid < o) red[tid] = fmaxf(red[tid], red[tid + o]);
        __syncthreads();
    }
    const float s = red[0] / 7.0f;                 // max|w|/7
    // write weight CODES (f32 or bf16 per tensor)
    for (int i = tid; i < nw; i += 256) {
        const float q = quantwc(loadT(w, i, isbf), s);   // CODE in [-7,7]
        switch (blk) {
            case 0: ws[W1C + i] = q; break;
            case 1: {                                    // [n][k] bf16, k=ci*9+kr*3+kc
                const int n = i / 252, k = i % 252;
                ((__hip_bfloat16*)(ws + W2B))[n * 256 + k] = __float2bfloat16(q);
            } break;
            case 2: ((__hip_bfloat16*)(ws + W3B))[i] = __float2bfloat16(q); break;
            case 3: {
                // transpose to [k][o], folding QuantFlatten transpose(3,2):
                // ref col f = c*9 + w*3 + h ; act3 flat k = c*9 + h*3 + w
                const int o = i / 576, f = i % 576;
                const int c = f / 9, fw_ = (f % 9) / 3, fh = f % 3;
                ((__hip_bfloat16*)(ws + FW1B))[(c * 9 + fh * 3 + fw_) * 128 + o] =
                    __float2bfloat16(q);
            } break;
            case 4: ws[BWC + i] = q; break;
            default: ws[CWC + i] = q; break;
        }
    }
    if (blk == 1) {        // zero-pad W2 k = 252..255
        for (int i = tid; i < 192; i += 256) {
            const int n = i / 4, k = 252 + (i % 4);
            ((__hip_bfloat16*)(ws + W2B))[n * 256 + k] = __float2bfloat16(0.f);
        }
    }
    const float den = pre * s;                     // Int32Bias scale
    for (int i = tid; i < nb; i += 256)
        ws[qbo + i] = rintf(loadT(b, i, isbf) / den);   // bias CODE
    if (tid == 0) ws[8 + blk] = den;               // p-scale for this layer
}

// ================= main fused per-sample kernel (code domain + MFMA conv2) ====
// LDS U[9952] = 39808 B -> 4 blocks/CU.
// persistent: ACT2@0 (768), ACT3@768 (576), ACT1bf16@1344 (1694 f = 3388 bf16)
__global__ __launch_bounds__(256, 4) void k_net(
    const void* __restrict__ x, const float* __restrict__ wsr,
    float* __restrict__ outp)
{
    __shared__ __align__(16) float U[9952];
    const int tid = threadIdx.x, b = blockIdx.x;
    const float sa0 = wsr[0], sa1 = wsr[1], sa2 = wsr[2], sa3 = wsr[3];
    const float sa4 = wsr[4], sab = wsr[5], sac = wsr[6];
    const float p1 = wsr[8], p2 = wsr[9], p3 = wsr[10], p4 = wsr[11];
    const float pB = wsr[12], pC = wsr[13];
    const int isbf = wsr[15] > 0.5f;
    constexpr int ACT2F = 0, ACT3F = 768, ACT1F = 1344;
    constexpr int XQF = 3040, W1F = 4840, B1F = 5596;            // P1/P2
    constexpr int AF = 3040, BFP = 4960, C2IF = 5920, B2CF = 9889; // P3
    constexpr int W3F = 3040, B3CF = 9184;                        // P4
    constexpr int PF = 3040, A4F = 3296, PARTF = 3424;            // P5/P6

    // ---- P1: input codes + conv1 weight codes ----
    for (int i = tid; i < 1728; i += 256) {
        const float v = loadT(x, (size_t)b * 1728 + i, isbf);
        const int ci = i / 576, r = (i % 576) / 24, c = i % 24;
        U[XQF + ci * 600 + r * 25 + c] = fminf(fmaxf(rintf(v / sa0), -8.f), 7.f);
    }
    for (int i = tid; i < 756; i += 256) U[W1F + i] = wsr[W1C + i];
    if (tid < 28) U[B1F + tid] = wsr[B1C + tid];
    __syncthreads();

    // ---- P2: conv1 rows + fused maxpool(3,2,ceil), sliding 3x5x3 reg window ----
    {
        __hip_bfloat16* act1w = (__hip_bfloat16*)(U + ACT1F);
        for (int item = tid; item < 308; item += 256) {
            const int o = item / 11, ph = item % 11;
            const int r0 = 2 * ph;
            const bool row2ok = (r0 + 2) < 22;
            float wk[27];
            #pragma unroll
            for (int i = 0; i < 27; ++i) wk[i] = U[W1F + o * 27 + i];
            const float bc = U[B1F + o];
            float w5[45];
            #pragma unroll
            for (int ci = 0; ci < 3; ++ci)
                #pragma unroll
                for (int ir = 0; ir < 5; ++ir)
                    #pragma unroll
                    for (int j = 0; j < 2; ++j)
                        w5[ci * 15 + ir * 3 + j] =
                            (r0 + ir < 24) ? U[XQF + ci * 600 + (r0 + ir) * 25 + j] : 0.f;
            float accP = -1e30f, accC = -1e30f;
            for (int c = 0; c < 22; ++c) {
                #pragma unroll
                for (int ci = 0; ci < 3; ++ci)
                    #pragma unroll
                    for (int ir = 0; ir < 5; ++ir)
                        w5[ci * 15 + ir * 3 + 2] =
                            (r0 + ir < 24) ? U[XQF + ci * 600 + (r0 + ir) * 25 + (c + 2)] : 0.f;
                float a0 = 0.f, a1 = 0.f, a2 = 0.f;
                #pragma unroll
                for (int ci = 0; ci < 3; ++ci)
                    #pragma unroll
                    for (int kr = 0; kr < 3; ++kr)
                        #pragma unroll
                        for (int kc = 0; kc < 3; ++kc) {
                            const float w = wk[ci * 9 + kr * 3 + kc];
                            a0 = fmaf(w5[ci * 15 + (kr + 0) * 3 + kc], w, a0);
                            a1 = fmaf(w5[ci * 15 + (kr + 1) * 3 + kc], w, a1);
                            a2 = fmaf(w5[ci * 15 + (kr + 2) * 3 + kc], w, a2);
                        }
                float cm = fmaxf(a0, a1);
                cm = row2ok ? fmaxf(cm, a2) : cm;
                if ((c & 1) == 0) {
                    if (c >= 2)
                        act1w[o * 121 + ph * 11 + (c / 2 - 1)] =
                            __float2bfloat16(qcode(fmaxf(accP, cm), bc, p1, sa1));
                    accC = cm;
                } else {
                    accC = fmaxf(accC, cm);
                    accP = accC;
                }
                #pragma unroll
                for (int ci = 0; ci < 3; ++ci)
                    #pragma unroll
                    for (int ir = 0; ir < 5; ++ir) {
                        w5[ci * 15 + ir * 3 + 0] = w5[ci * 15 + ir * 3 + 1];
                        w5[ci * 15 + ir * 3 + 1] = w5[ci * 15 + ir * 3 + 2];
                    }
            }
            act1w[o * 121 + ph * 11 + 10] =
                __float2bfloat16(qcode(accP, bc, p1, sa1));   // ceil edge
        }
    }
    __syncthreads();

    // ---- P3: conv2 via MFMA (M=96 spatial, N=48 ch, K=256) + pool + quant ----
    {
        const unsigned short* act1u = (const unsigned short*)(U + ACT1F);
        unsigned short* Au = (unsigned short*)(U + AF);      // A [96][40] bf16
        unsigned short* Bu = (unsigned short*)(U + BFP);     // B [48][40] bf16 (n-major)
        const unsigned short* w2u = (const unsigned short*)(wsr + W2B);
        if (tid < 48) U[B2CF + tid] = wsr[B2C + tid];
        const int kloc = tid & 31, g = tid >> 5;
        const int wv = tid >> 6, lane = tid & 63;
        f32x4v acc[5];
        #pragma unroll
        for (int j = 0; j < 5; ++j) { acc[j][0]=0.f; acc[j][1]=0.f; acc[j][2]=0.f; acc[j][3]=0.f; }
        for (int kk = 0; kk < 8; ++kk) {
            const int k = kk * 32 + kloc;
            const bool kok = (k < 252);
            const int ci = kok ? k / 9 : 0;
            const int kr = kok ? (k % 9) / 3 : 0, kc = kok ? k % 3 : 0;
            #pragma unroll
            for (int e = 0; e < 12; ++e) {
                const int s = g + 8 * e;                 // 0..95
                unsigned short v = 0;
                if (kok && s < 81) {
                    const int r = s / 9, c = s % 9;
                    v = act1u[ci * 121 + (r + kr) * 11 + (c + kc)];
                }
                Au[s * 40 + kloc] = v;
            }
            #pragma unroll
            for (int e = 0; e < 6; ++e) {
                const int n = g + 8 * e;                 // 0..47
                Bu[n * 40 + kloc] = w2u[n * 256 + k];    // k-pad already zeroed
            }
            __syncthreads();
            #pragma unroll
            for (int j = 0; j < 5; ++j) {
                const int t = wv + 4 * j;
                if (t < 18) {
                    const int tm = t / 3, tn = t % 3;
                    bf16x8v af = *(const bf16x8v*)(Au + (tm * 16 + (lane & 15)) * 40 + (lane >> 4) * 8);
                    bf16x8v bfv = *(const bf16x8v*)(Bu + (tn * 16 + (lane & 15)) * 40 + (lane >> 4) * 8);
                    acc[j] = __builtin_amdgcn_mfma_f32_16x16x32_bf16(af, bfv, acc[j], 0, 0, 0);
                }
            }
            __syncthreads();
        }
        // scatter integer C to [81][49]
        #pragma unroll
        for (int j = 0; j < 5; ++j) {
            const int t = wv + 4 * j;
            if (t < 18) {
                const int tm = t / 3, tn = t % 3;
                const int col = tn * 16 + (lane & 15);
                #pragma unroll
                for (int r = 0; r < 4; ++r) {
                    const int row = tm * 16 + (lane >> 4) * 4 + r;
                    if (row < 81) U[C2IF + row * 49 + col] = acc[j][r];
                }
            }
        }
        __syncthreads();
        // pool(3,2) + bias + quant -> ACT2 codes [48][16]
        for (int id = tid; id < 768; id += 256) {
            const int ch = id >> 4, pp = id & 15, ph = pp >> 2, pw = pp & 3;
            float mx = -1e30f;
            #pragma unroll
            for (int r = 0; r < 3; ++r)
                #pragma unroll
                for (int c = 0; c < 3; ++c)
                    mx = fmaxf(mx, U[C2IF + ((2 * ph + r) * 9 + (2 * pw + c)) * 49 + ch]);
            U[ACT2F + ch * 16 + pp] = qcode(mx, U[B2CF + ch], p2, sa2);
        }
    }
    __syncthreads();

    // ---- P4: conv3 (all 64 ch, W3 bf16 codes in LDS) ----
    for (int i = tid; i < 6144; i += 256) U[W3F + i] = wsr[W3B + i];  // raw bits
    if (tid < 64) U[B3CF + tid] = wsr[B3C + tid];
    __syncthreads();
    if (tid < 192) {                         // (o, hq): 64*3, 3 cols each
        const int o = tid / 3, hq = tid % 3;
        const unsigned* w3u = (const unsigned*)(U + W3F);
        float a0 = 0.f, a1 = 0.f, a2 = 0.f;
        for (int ci = 0; ci < 48; ++ci) {
            const unsigned pa = w3u[o * 96 + ci * 2];        // w00,w01
            const unsigned pb = w3u[o * 96 + ci * 2 + 1];    // w10,w11
            const float w00 = bfbits(pa & 0xffffu), w01 = bfbits(pa >> 16);
            const float w10 = bfbits(pb & 0xffffu), w11 = bfbits(pb >> 16);
            const int xb = ACT2F + ci * 16;
            float r0[4], r1[4];
            #pragma unroll
            for (int c = 0; c < 4; ++c) {
                r0[c] = U[xb + hq * 4 + c];
                r1[c] = U[xb + (hq + 1) * 4 + c];
            }
            a0 = fmaf(r0[0], w00, a0); a0 = fmaf(r0[1], w01, a0);
            a0 = fmaf(r1[0], w10, a0); a0 = fmaf(r1[1], w11, a0);
            a1 = fmaf(r0[1], w00, a1); a1 = fmaf(r0[2], w01, a1);
            a1 = fmaf(r1[1], w10, a1); a1 = fmaf(r1[2], w11, a1);
            a2 = fmaf(r0[2], w00, a2); a2 = fmaf(r0[3], w01, a2);
            a2 = fmaf(r1[2], w10, a2); a2 = fmaf(r1[3], w11, a2);
        }
        const float bc = U[B3CF + o];
        U[ACT3F + o * 9 + hq * 3 + 0] = qcode(a0, bc, p3, sa3);
        U[ACT3F + o * 9 + hq * 3 + 1] = qcode(a1, bc, p3, sa3);
        U[ACT3F + o * 9 + hq * 3 + 2] = qcode(a2, bc, p3, sa3);
    }
    __syncthreads();

    // ---- P5: fc1 (576->128), bf16 code weights streamed from L2 ----
    {
        const int o = tid & 127, half = tid >> 7;
        const __hip_bfloat16* fwb = (const __hip_bfloat16*)(wsr + FW1B);
        float acc = 0.f;
        const int k0 = half * 288;
        for (int k = k0; k < k0 + 288; ++k)
            acc = fmaf(U[ACT3F + k], __bfloat162float(fwb[k * 128 + o]), acc);
        U[PF + tid] = acc;
    }
    __syncthreads();
    if (tid < 128) {
        const float C = U[PF + tid] + U[PF + 128 + tid];
        U[A4F + tid] = qcode(C, wsr[FB1C + tid], p4, sa4);
    }
    __syncthreads();

    // ---- P6: heads + final signed quant ----
    if (tid < 96) {
        const int d = tid >> 4, gq = tid & 15;
        const float* hw = (d < 4) ? (wsr + BWC + d * 128) : (wsr + CWC + (d - 4) * 128);
        float p = 0.f;
        #pragma unroll
        for (int k = 0; k < 8; ++k)
            p = fmaf(U[A4F + gq * 8 + k], hw[gq * 8 + k], p);
        U[PARTF + d * 16 + gq] = p;
    }
    __syncthreads();
    if (tid < 6) {
        float C = (tid < 4) ? wsr[BBC + tid] : wsr[CBC + (tid - 4)];
        for (int g = 0; g < 16; ++g) C += U[PARTF + tid * 16 + g];
        if (tid < 4) {
            const float val = C * pB;
            outp[(size_t)b * 4 + tid] = fminf(fmaxf(rintf(val / sab), -8.f), 7.f) * sab;
        } else {
            const float val = C * pC;
            outp[16384 + (size_t)b * 2 + (tid - 4)] =
                fminf(fmaxf(rintf(val / sac), -8.f), 7.f) * sac;
        }
    }
}

// ================= fallback: R7 self-contained kernel (proven) =================
__global__ __launch_bounds__(256) void k_net_fb(
    const void* __restrict__ x,
    const void* __restrict__ w1,  const void* __restrict__ b1,
    const void* __restrict__ w2,  const void* __restrict__ b2,
    const void* __restrict__ w3,  const void* __restrict__ b3,
    const void* __restrict__ fw1, const void* __restrict__ fb1,
    const void* __restrict__ bw,  const void* __restrict__ bb,
    const void* __restrict__ cw,  const void* __restrict__ cb,
    const void* __restrict__ s0p, const void* __restrict__ s1p,
    const void* __restrict__ s2p, const void* __restrict__ s3p,
    const void* __restrict__ s4p, const void* __restrict__ s5p,
    const void* __restrict__ s6p,
    float* __restrict__ outp)
{
    __shared__ float U[16000];
    __shared__ float swsh[8];
    __shared__ float sash[8];
    const int tid = threadIdx.x;
    const int b   = blockIdx.x;
    constexpr int RED = 0, XQ = 0, W1Q = 1728, B1Q = 2484, C1 = 2512;
    constexpr int ACT1 = 9288, WB = 0, C2 = 12676, ACT2 = 14620, ACT3 = 15388;
    constexpr int A4 = 0, PART = 128;

    if (tid == 0) {
        const unsigned short* hb = (const unsigned short*)w1;
        int zeros = 0, sane = 0;
        for (int i = 0; i < 64; ++i) {
            unsigned short u = hb[2 * i];
            float v = __uint_as_float(((unsigned int)u) << 16);
            float a = fabsf(v);
            if (a == 0.f) zeros++;
            else if (a > 1e-8f && a < 1e4f) sane++;
        }
        swsh[7] = (zeros < 40 && sane >= 40) ? 1.f : 0.f;
        const void* sp[7] = { s0p, s1p, s2p, s3p, s4p, s5p, s6p };
        for (int j = 0; j < 7; ++j) {
            float v = *(const float*)sp[j];
            float a = fabsf(v);
            if (!(a > 1e-6f && a < 1e6f)) {
                double d = *(const double*)sp[j];
                double ad = fabs(d);
                if (ad > 1e-6 && ad < 1e6) v = (float)d;
                else {
                    unsigned short u = *(const unsigned short*)sp[j];
                    v = __uint_as_float(((unsigned int)u) << 16);
                }
            }
            sash[j] = v;
        }
    }
    __syncthreads();
    const int isbf = swsh[7] > 0.5f;
    {
        const void* wp[6] = { w1, w2, w3, fw1, bw, cw };
        const int   wn[6] = { 756, 12096, 12288, 73728, 512, 256 };
        for (int j = 0; j < 6; ++j) {
            float m = 0.f;
            for (int i = tid; i < wn[j]; i += 256)
                m = fmaxf(m, fabsf(loadT(wp[j], i, isbf)));
            U[RED + tid] = m; __syncthreads();
            for (int o = 128; o > 0; o >>= 1) {
                if (tid < o) U[RED + tid] = fmaxf(U[RED + tid], U[RED + tid + o]);
                __syncthreads();
            }
            if (tid == 0) swsh[j] = U[RED] / 7.0f;
            __syncthreads();
        }
    }
    const float sa0 = sash[0], sa1 = sash[1], sa2 = sash[2], sa3 = sash[3];
    const float sa4 = sash[4], sab = sash[5], sac = sash[6];
    const float sw1s = swsh[0], sw2s = swsh[1], sw3s = swsh[2];
    const float sw4s = swsh[3], swbs = swsh[4], swcs = swsh[5];

    for (int i = tid; i < 1728; i += 256) {
        float v = loadT(x, (size_t)b * 1728 + i, isbf);
        U[XQ + i] = fminf(fmaxf(rintf(v / sa0), -8.f), 7.f) * sa0;
    }
    for (int i = tid; i < 756; i += 256) U[W1Q + i] = quantw(loadT(w1, i, isbf), sw1s);
    {
        const float den = sa0 * sw1s;
        for (int i = tid; i < 28; i += 256) U[B1Q + i] = qbias(loadT(b1, i, isbf), den);
    }
    __syncthreads();

    for (int g = 0; g < 2; ++g) {
        const int obase = g * 14;
        for (int idx = tid; idx < 308; idx += 256) {
            const int ol = idx / 22, r = idx % 22, o = obase + ol;
            for (int c = 0; c < 22; ++c) {
                float acc = 0.f;
                #pragma unroll
                for (int ci = 0; ci < 3; ++ci)
                    #pragma unroll
                    for (int kr = 0; kr < 3; ++kr)
                        #pragma unroll
                        for (int kc = 0; kc < 3; ++kc)
                            acc = fmaf(U[XQ + ci * 576 + (r + kr) * 24 + (c + kc)],
                                       U[W1Q + o * 27 + ci * 9 + kr * 3 + kc], acc);
                U[C1 + ol * 484 + r * 22 + c] = acc + U[B1Q + o];
            }
        }
        __syncthreads();
        for (int i = tid; i < 1694; i += 256) {
            const int ol = i / 121, rem = i % 121, ph = rem / 11, pw = rem % 11;
            const int r0 = 2 * ph, c0 = 2 * pw;
            const int r1 = min(r0 + 3, 22), c1 = min(c0 + 3, 22);
            float mx = -1e30f;
            for (int r = r0; r < r1; ++r)
                for (int c = c0; c < c1; ++c)
                    mx = fmaxf(mx, U[C1 + ol * 484 + r * 22 + c]);
            U[ACT1 + (obase + ol) * 121 + rem] = qrelu(mx, sa1);
        }
        __syncthreads();
    }

    for (int h = 0; h < 2; ++h) {
        const int obase = h * 24;
        for (int i = tid; i < 6048; i += 256)
            U[WB + i] = quantw(loadT(w2, (size_t)h * 6048 + i, isbf), sw2s);
        {
            const float den = sa1 * sw2s;
            for (int i = tid; i < 24; i += 256)
                U[WB + 6048 + i] = qbias(loadT(b2, obase + i, isbf), den);
        }
        __syncthreads();
        for (int idx = tid; idx < 216; idx += 256) {
            const int ol = idx / 9, r = idx % 9;
            for (int c = 0; c < 9; ++c) {
                float acc = 0.f;
                for (int ci = 0; ci < 28; ++ci)
                    #pragma unroll
                    for (int kr = 0; kr < 3; ++kr)
                        #pragma unroll
                        for (int kc = 0; kc < 3; ++kc)
                            acc = fmaf(U[ACT1 + ci * 121 + (r + kr) * 11 + (c + kc)],
                                       U[WB + ol * 252 + ci * 9 + kr * 3 + kc], acc);
                U[C2 + ol * 81 + r * 9 + c] = acc + U[WB + 6048 + ol];
            }
        }
        __syncthreads();
        for (int i = tid; i < 384; i += 256) {
            const int ol = i / 16, ph = (i % 16) / 4, pw = i % 4;
            float mx = -1e30f;
            #pragma unroll
            for (int r = 0; r < 3; ++r)
                #pragma unroll
                for (int c = 0; c < 3; ++c)
                    mx = fmaxf(mx, U[C2 + ol * 81 + (2 * ph + r) * 9 + (2 * pw + c)]);
            U[ACT2 + (obase + ol) * 16 + (i % 16)] = qrelu(mx, sa2);
        }
        __syncthreads();
    }

    for (int h = 0; h < 2; ++h) {
        const int obase = h * 32;
        for (int i = tid; i < 6144; i += 256)
            U[WB + i] = quantw(loadT(w3, (size_t)h * 6144 + i, isbf), sw3s);
        {
            const float den = sa2 * sw3s;
            for (int i = tid; i < 32; i += 256)
                U[WB + 6144 + i] = qbias(loadT(b3, obase + i, isbf), den);
        }
        __syncthreads();
        for (int idx = tid; idx < 288; idx += 256) {
            const int ol = idx / 9, hh = (idx % 9) / 3, ww = idx % 3;
            float acc = 0.f;
            for (int ci = 0; ci < 48; ++ci) {
                const int xb2 = ACT2 + ci * 16;
                const int wb2 = WB + ol * 192 + ci * 4;
                acc = fmaf(U[xb2 + hh * 4 + ww],           U[wb2 + 0], acc);
                acc = fmaf(U[xb2 + hh * 4 + ww + 1],       U[wb2 + 1], acc);
                acc = fmaf(U[xb2 + (hh + 1) * 4 + ww],     U[wb2 + 2], acc);
                acc = fmaf(U[xb2 + (hh + 1) * 4 + ww + 1], U[wb2 + 3], acc);
            }
            acc += U[WB + 6144 + ol];
            U[ACT3 + (obase + ol) * 9 + hh * 3 + ww] = qrelu(acc, sa3);
        }
        __syncthreads();
    }

    {
        const int wave = tid >> 6, lane = tid & 63;
        const float den = sa3 * sw4s;
        for (int oo = 0; oo < 32; ++oo) {
            const int o = wave * 32 + oo;
            float acc = 0.f;
            #pragma unroll
            for (int j = 0; j < 9; ++j) {
                const int f = lane + 64 * j;
                const int c = f / 9, fw = (f % 9) / 3, fh = f % 3;
                const float av = U[ACT3 + c * 9 + fh * 3 + fw];
                const float wv = quantw(loadT(fw1, (size_t)o * 576 + f, isbf), sw4s);
                acc = fmaf(av, wv, acc);
            }
            #pragma unroll
            for (int off = 32; off > 0; off >>= 1)
                acc += __shfl_down(acc, off);
            if (lane == 0) {
                acc += qbias(loadT(fb1, o, isbf), den);
                U[A4 + o] = qrelu(acc, sa4);
            }
        }
    }
    __syncthreads();

    if (tid < 96) {
        const int d = tid >> 4, g = tid & 15;
        const void* hw = (d < 4) ? bw : cw;
        const int row = (d < 4) ? d : d - 4;
        const float swh = (d < 4) ? swbs : swcs;
        float p = 0.f;
        #pragma unroll
        for (int k = 0; k < 8; ++k) {
            const int kk = g * 8 + k;
            p = fmaf(U[A4 + kk], quantw(loadT(hw, row * 128 + kk, isbf), swh), p);
        }
        U[PART + d * 16 + g] = p;
    }
    __syncthreads();
    if (tid < 6) {
        const int d = tid;
        float acc;
        if (d < 4) acc = qbias(loadT(bb, d, isbf), sa4 * swbs);
        else       acc = qbias(loadT(cb, d - 4, isbf), sa4 * swcs);
        for (int g = 0; g < 16; ++g) acc += U[PART + d * 16 + g];
        if (d < 4) outp[(size_t)b * 4 + d] = fminf(fmaxf(rintf(acc / sab), -8.f), 7.f) * sab;
        else outp[16384 + (size_t)b * 2 + (d - 4)] = fminf(fmaxf(rintf(acc / sac), -8.f), 7.f) * sac;
    }
}

extern "C" void kernel_launch(void* const* d_in, const int* in_sizes, int n_in,
                              void* d_out, int out_size, void* d_ws, size_t ws_size,
                              hipStream_t stream)
{
    float* out = (float*)d_out;
    const int expect[20] = { 7077888, 756, 28, 12096, 48, 12288, 64, 73728, 128,
                             512, 4, 256, 2, 1, 1, 1, 1, 1, 1, 1 };
    if (n_in < 20) { k_beacon<<<1, 64, 0, stream>>>(out, 9000.f); return; }
    for (int i = 0; i < 20; ++i)
        if (in_sizes[i] != expect[i]) {
            k_beacon<<<1, 64, 0, stream>>>(out, 2000.f + 10.f * i);
            return;
        }

    if (ws_size >= (size_t)100000 * sizeof(float)) {
        float* ws = (float*)d_ws;
        k_prep<<<6, 256, 0, stream>>>(
            d_in[1], d_in[2], d_in[3], d_in[4], d_in[5], d_in[6],
            d_in[7], d_in[8], d_in[9], d_in[10], d_in[11], d_in[12],
            d_in[13], d_in[14], d_in[15], d_in[16], d_in[17], d_in[18], d_in[19],
            ws);
        k_net<<<4096, 256, 0, stream>>>(d_in[0], ws, out);
    } else {
        k_net_fb<<<4096, 256, 0, stream>>>(
            d_in[0], d_in[1], d_in[2], d_in[3], d_in[4], d_in[5], d_in[6],
            d_in[7], d_in[8], d_in[9], d_in[10], d_in[11], d_in[12],
            d_in[13], d_in[14], d_in[15], d_in[16], d_in[17], d_in[18], d_in[19],
            out);
    }
}

// Round 11
// 224.126 us; speedup vs baseline: 10.5021x; 1.7816x over previous
//
#include <hip/hip_runtime.h>
#include <hip/hip_bf16.h>
#include <math.h>

typedef __attribute__((ext_vector_type(8))) short bf16x8v;   // 8 bf16 (4 VGPR)
typedef __attribute__((ext_vector_type(4))) float f32x4v;

// ================= shared helpers =================
__device__ __forceinline__ float loadT(const void* p, size_t i, int isbf) {
    if (isbf) return __bfloat162float(((const __hip_bfloat16*)p)[i]);
    return ((const float*)p)[i];
}
__device__ __forceinline__ float quantw(float v, float s) {      // weight VALUE
    return fminf(fmaxf(rintf(v / s), -7.f), 7.f) * s;
}
__device__ __forceinline__ float quantwc(float v, float s) {     // weight CODE
    return fminf(fmaxf(rintf(v / s), -7.f), 7.f);
}
__device__ __forceinline__ float qbias(float v, float den) {     // Int32Bias VALUE
    return rintf(v / den) * den;
}
__device__ __forceinline__ float qrelu(float v, float s) {       // [0,15] VALUE
    return fminf(fmaxf(rintf(fmaxf(v, 0.f) / s), 0.f), 15.f) * s;
}
// code-domain quant-relu: Cint+bias code -> next-layer code
__device__ __forceinline__ float qcode(float Cint, float bcode, float p, float snext) {
    float v = (Cint + bcode) * p;
    return fminf(fmaxf(rintf(fmaxf(v, 0.f) / snext), 0.f), 15.f);
}
__device__ __forceinline__ float bfbits(unsigned u) {            // bf16 bits -> f32
    return __uint_as_float(u << 16);
}

__global__ void k_beacon(float* out, float code) {
    if (threadIdx.x == 0 && blockIdx.x == 0) out[0] = code;
}

// ================= ws layout (floats) =================
// [0..6]=sa0..sa4,sab,sac ; [8..13]=p1,p2,p3,p4,pB,pC ; [15]=isbf
static constexpr int W1C  = 16;     // 756   f32 codes
static constexpr int B1C  = 772;    // 28    f32 codes
static constexpr int B2C  = 800;    // 48
static constexpr int B3C  = 848;    // 64
static constexpr int FB1C = 912;    // 128
static constexpr int BBC  = 1040;   // 4
static constexpr int CBC  = 1044;   // 2
static constexpr int FW1B = 1048;   // 36864 floats = 73728 bf16 codes [k][o]
static constexpr int W2B  = 37912;  // 6144 floats = 12288 bf16 codes [48][256] (k-pad)
static constexpr int W3B  = 44056;  // 6144 floats = 12288 bf16 codes [64][48][2][2]
static constexpr int BWC  = 50200;  // 512  f32 codes
static constexpr int CWC  = 50712;  // 256  f32 codes
static constexpr int PMAXF = 51000; // 35 partial-max slots -> end 51035 (~204 KB)

// chunks per tensor {w1,w2,w3,fw1,bw,cw} and block-offset prefix
__device__ __constant__ int d_CHK[6]  = { 1, 4, 4, 24, 1, 1 };
__device__ __constant__ int d_POFF[7] = { 0, 1, 5, 9, 33, 34, 35 };

// ============ k_scale: partial maxes (35 blocks) + probe + act scales ============
__global__ __launch_bounds__(256) void k_scale(
    const void* w1, const void* w2, const void* w3, const void* fw1,
    const void* bw, const void* cw,
    const void* s0p, const void* s1p, const void* s2p, const void* s3p,
    const void* s4p, const void* s5p, const void* s6p,
    float* __restrict__ ws)
{
    __shared__ float red[256];
    __shared__ float shisbf;
    const int tid = threadIdx.x, blk = blockIdx.x;
    // wave-parallel storage-format probe (1 load/lane + ballot)
    if (tid < 64) {
        const unsigned short* hb = (const unsigned short*)w1;
        const float a = fabsf(bfbits((unsigned)hb[2 * tid]));
        const unsigned long long bz = __ballot(a == 0.f);
        const unsigned long long bs = __ballot(a > 1e-8f && a < 1e4f);
        if (tid == 0) {
            const int zeros = __popcll(bz), sane = __popcll(bs);
            shisbf = (zeros < 40 && sane >= 40) ? 1.f : 0.f;
        }
    }
    __syncthreads();
    const int isbf = shisbf > 0.5f;
    if (blk == 0) {
        if (tid == 7) ws[15] = shisbf;
        if (tid < 7) {                       // 7 scales read in parallel
            const void* sp[7] = { s0p, s1p, s2p, s3p, s4p, s5p, s6p };
            const void* p = sp[tid];
            float v = *(const float*)p;
            float a = fabsf(v);
            if (!(a > 1e-6f && a < 1e6f)) {
                double d = *(const double*)p;
                double ad = fabs(d);
                if (ad > 1e-6 && ad < 1e6) v = (float)d;
                else v = bfbits((unsigned)(*(const unsigned short*)p));
            }
            ws[tid] = v;
        }
    }
    // tensor/chunk for this block
    int j = 0;
    while (j < 5 && blk >= d_POFF[j + 1]) ++j;
    const int c = blk - d_POFF[j];
    const void* wp[6] = { w1, w2, w3, fw1, bw, cw };
    const int   wn[6] = { 756, 12096, 12288, 73728, 512, 256 };
    const int nw = wn[j];
    const int len = (nw + d_CHK[j] - 1) / d_CHK[j];
    const int i0 = c * len, i1 = min(i0 + len, nw);
    float m = 0.f;
    for (int i = i0 + tid; i < i1; i += 256)
        m = fmaxf(m, fabsf(loadT(wp[j], i, isbf)));
    red[tid] = m; __syncthreads();
    for (int o = 128; o > 0; o >>= 1) {
        if (tid < o) red[tid] = fmaxf(red[tid], red[tid + o]);
        __syncthreads();
    }
    if (tid == 0) ws[PMAXF + blk] = red[0];
}

// ============ k_quant: quantize all weights/biases (34 blocks, short trips) ======
__global__ __launch_bounds__(256) void k_quant(
    const void* w1, const void* b1, const void* w2, const void* b2,
    const void* w3, const void* b3, const void* fw1, const void* fb1,
    const void* bw, const void* bb, const void* cw, const void* cb,
    float* __restrict__ ws)
{
    const int tid = threadIdx.x, blk = blockIdx.x;
    const int isbf = ws[15] > 0.5f;
    auto getscale = [&](int j) {
        float m = 0.f;
        for (int t = d_POFF[j]; t < d_POFF[j + 1]; ++t)
            m = fmaxf(m, ws[PMAXF + t]);
        return m / 7.0f;
    };

    if (blk < 24) {                          // fw1 -> FW1B bf16 [k][o]
        const float s = getscale(3);
        const int i0 = blk * 3072, i1 = min(i0 + 3072, 73728);
        __hip_bfloat16* dst = (__hip_bfloat16*)(ws + FW1B);
        for (int i = i0 + tid; i < i1; i += 256) {
            const float q = quantwc(loadT(fw1, i, isbf), s);
            const int o = i / 576, f = i % 576;
            const int c = f / 9, fw_ = (f % 9) / 3, fh = f % 3;
            dst[(c * 9 + fh * 3 + fw_) * 128 + o] = __float2bfloat16(q);
        }
    } else if (blk < 28) {                   // w2 -> W2B bf16 [48][256]
        const float s = getscale(1);
        const int c = blk - 24;
        const int i0 = c * 3024, i1 = min(i0 + 3024, 12096);
        __hip_bfloat16* dst = (__hip_bfloat16*)(ws + W2B);
        for (int i = i0 + tid; i < i1; i += 256) {
            const float q = quantwc(loadT(w2, i, isbf), s);
            const int n = i / 252, k = i % 252;
            dst[n * 256 + k] = __float2bfloat16(q);
        }
        if (c == 0) {                        // zero-pad k = 252..255
            for (int i = tid; i < 192; i += 256) {
                const int n = i / 4, k = 252 + (i % 4);
                dst[n * 256 + k] = __float2bfloat16(0.f);
            }
        }
    } else if (blk < 32) {                   // w3 -> W3B bf16 [i]
        const float s = getscale(2);
        const int c = blk - 28;
        const int i0 = c * 3072, i1 = min(i0 + 3072, 12288);
        __hip_bfloat16* dst = (__hip_bfloat16*)(ws + W3B);
        for (int i = i0 + tid; i < i1; i += 256)
            dst[i] = __float2bfloat16(quantwc(loadT(w3, i, isbf), s));
    } else if (blk == 32) {                  // w1 -> W1C f32 codes
        const float s = getscale(0);
        for (int i = tid; i < 756; i += 256)
            ws[W1C + i] = quantwc(loadT(w1, i, isbf), s);
    } else {                                 // heads + all bias codes + p-scales
        const float s0 = getscale(0), s1 = getscale(1), s2 = getscale(2);
        const float s3 = getscale(3), s4 = getscale(4), s5 = getscale(5);
        const float sa0 = ws[0], sa1 = ws[1], sa2 = ws[2], sa3 = ws[3], sa4 = ws[4];
        for (int i = tid; i < 512; i += 256) ws[BWC + i] = quantwc(loadT(bw, i, isbf), s4);
        for (int i = tid; i < 256; i += 256) ws[CWC + i] = quantwc(loadT(cw, i, isbf), s5);
        if (tid < 28)  ws[B1C + tid]  = rintf(loadT(b1, tid, isbf)  / (sa0 * s0));
        if (tid < 48)  ws[B2C + tid]  = rintf(loadT(b2, tid, isbf)  / (sa1 * s1));
        if (tid < 64)  ws[B3C + tid]  = rintf(loadT(b3, tid, isbf)  / (sa2 * s2));
        if (tid < 128) ws[FB1C + tid] = rintf(loadT(fb1, tid, isbf) / (sa3 * s3));
        if (tid < 4)   ws[BBC + tid]  = rintf(loadT(bb, tid, isbf)  / (sa4 * s4));
        if (tid < 2)   ws[CBC + tid]  = rintf(loadT(cb, tid, isbf)  / (sa4 * s5));
        if (tid == 0) {
            ws[8]  = sa0 * s0;   // p1
            ws[9]  = sa1 * s1;   // p2
            ws[10] = sa2 * s2;   // p3
            ws[11] = sa3 * s3;   // p4
            ws[12] = sa4 * s4;   // pB
            ws[13] = sa4 * s5;   // pC
        }
    }
}

// ================= main fused per-sample kernel (code domain + MFMA conv2) ====
// LDS U[9952] = 39808 B -> 4 blocks/CU.
// persistent: ACT2@0 (768), ACT3@768 (576), ACT1bf16@1344 (1694 f = 3388 bf16)
__global__ __launch_bounds__(256, 4) void k_net(
    const void* __restrict__ x, const float* __restrict__ wsr,
    float* __restrict__ outp)
{
    __shared__ __align__(16) float U[9952];
    const int tid = threadIdx.x, b = blockIdx.x;
    const float sa0 = wsr[0], sa1 = wsr[1], sa2 = wsr[2], sa3 = wsr[3];
    const float sa4 = wsr[4], sab = wsr[5], sac = wsr[6];
    const float p1 = wsr[8], p2 = wsr[9], p3 = wsr[10], p4 = wsr[11];
    const float pB = wsr[12], pC = wsr[13];
    const int isbf = wsr[15] > 0.5f;
    constexpr int ACT2F = 0, ACT3F = 768, ACT1F = 1344;
    constexpr int XQF = 3040, W1F = 4840, B1F = 5596;            // P1/P2
    constexpr int AF = 3040, BFP = 4960, C2IF = 5920, B2CF = 9889; // P3
    constexpr int W3F = 3040, B3CF = 9184;                        // P4
    constexpr int PF = 3040, A4F = 3296, PARTF = 3424;            // P5/P6

    // ---- P1: input codes + conv1 weight codes ----
    for (int i = tid; i < 1728; i += 256) {
        const float v = loadT(x, (size_t)b * 1728 + i, isbf);
        const int ci = i / 576, r = (i % 576) / 24, c = i % 24;
        U[XQF + ci * 600 + r * 25 + c] = fminf(fmaxf(rintf(v / sa0), -8.f), 7.f);
    }
    for (int i = tid; i < 756; i += 256) U[W1F + i] = wsr[W1C + i];
    if (tid < 28) U[B1F + tid] = wsr[B1C + tid];
    __syncthreads();

    // ---- P2: conv1 rows + fused maxpool(3,2,ceil), sliding 3x5x3 reg window ----
    {
        __hip_bfloat16* act1w = (__hip_bfloat16*)(U + ACT1F);
        for (int item = tid; item < 308; item += 256) {
            const int o = item / 11, ph = item % 11;
            const int r0 = 2 * ph;
            const bool row2ok = (r0 + 2) < 22;
            float wk[27];
            #pragma unroll
            for (int i = 0; i < 27; ++i) wk[i] = U[W1F + o * 27 + i];
            const float bc = U[B1F + o];
            float w5[45];
            #pragma unroll
            for (int ci = 0; ci < 3; ++ci)
                #pragma unroll
                for (int ir = 0; ir < 5; ++ir)
                    #pragma unroll
                    for (int j = 0; j < 2; ++j)
                        w5[ci * 15 + ir * 3 + j] =
                            (r0 + ir < 24) ? U[XQF + ci * 600 + (r0 + ir) * 25 + j] : 0.f;
            float accP = -1e30f, accC = -1e30f;
            for (int c = 0; c < 22; ++c) {
                #pragma unroll
                for (int ci = 0; ci < 3; ++ci)
                    #pragma unroll
                    for (int ir = 0; ir < 5; ++ir)
                        w5[ci * 15 + ir * 3 + 2] =
                            (r0 + ir < 24) ? U[XQF + ci * 600 + (r0 + ir) * 25 + (c + 2)] : 0.f;
                float a0 = 0.f, a1 = 0.f, a2 = 0.f;
                #pragma unroll
                for (int ci = 0; ci < 3; ++ci)
                    #pragma unroll
                    for (int kr = 0; kr < 3; ++kr)
                        #pragma unroll
                        for (int kc = 0; kc < 3; ++kc) {
                            const float w = wk[ci * 9 + kr * 3 + kc];
                            a0 = fmaf(w5[ci * 15 + (kr + 0) * 3 + kc], w, a0);
                            a1 = fmaf(w5[ci * 15 + (kr + 1) * 3 + kc], w, a1);
                            a2 = fmaf(w5[ci * 15 + (kr + 2) * 3 + kc], w, a2);
                        }
                float cm = fmaxf(a0, a1);
                cm = row2ok ? fmaxf(cm, a2) : cm;
                if ((c & 1) == 0) {
                    if (c >= 2)
                        act1w[o * 121 + ph * 11 + (c / 2 - 1)] =
                            __float2bfloat16(qcode(fmaxf(accP, cm), bc, p1, sa1));
                    accC = cm;
                } else {
                    accC = fmaxf(accC, cm);
                    accP = accC;
                }
                #pragma unroll
                for (int ci = 0; ci < 3; ++ci)
                    #pragma unroll
                    for (int ir = 0; ir < 5; ++ir) {
                        w5[ci * 15 + ir * 3 + 0] = w5[ci * 15 + ir * 3 + 1];
                        w5[ci * 15 + ir * 3 + 1] = w5[ci * 15 + ir * 3 + 2];
                    }
            }
            act1w[o * 121 + ph * 11 + 10] =
                __float2bfloat16(qcode(accP, bc, p1, sa1));   // ceil edge
        }
    }
    __syncthreads();

    // ---- P3: conv2 via MFMA (M=96 spatial, N=48 ch, K=256) + pool + quant ----
    {
        const unsigned short* act1u = (const unsigned short*)(U + ACT1F);
        unsigned short* Au = (unsigned short*)(U + AF);      // A [96][40] bf16
        unsigned short* Bu = (unsigned short*)(U + BFP);     // B [48][40] bf16 (n-major)
        const unsigned short* w2u = (const unsigned short*)(wsr + W2B);
        if (tid < 48) U[B2CF + tid] = wsr[B2C + tid];
        const int kloc = tid & 31, g = tid >> 5;
        const int wv = tid >> 6, lane = tid & 63;
        f32x4v acc[5];
        #pragma unroll
        for (int j = 0; j < 5; ++j) { acc[j][0]=0.f; acc[j][1]=0.f; acc[j][2]=0.f; acc[j][3]=0.f; }
        for (int kk = 0; kk < 8; ++kk) {
            const int k = kk * 32 + kloc;
            const bool kok = (k < 252);
            const int ci = kok ? k / 9 : 0;
            const int kr = kok ? (k % 9) / 3 : 0, kc = kok ? k % 3 : 0;
            #pragma unroll
            for (int e = 0; e < 12; ++e) {
                const int s = g + 8 * e;                 // 0..95
                unsigned short v = 0;
                if (kok && s < 81) {
                    const int r = s / 9, c = s % 9;
                    v = act1u[ci * 121 + (r + kr) * 11 + (c + kc)];
                }
                Au[s * 40 + kloc] = v;
            }
            #pragma unroll
            for (int e = 0; e < 6; ++e) {
                const int n = g + 8 * e;                 // 0..47
                Bu[n * 40 + kloc] = w2u[n * 256 + k];    // k-pad already zeroed
            }
            __syncthreads();
            #pragma unroll
            for (int j = 0; j < 5; ++j) {
                const int t = wv + 4 * j;
                if (t < 18) {
                    const int tm = t / 3, tn = t % 3;
                    bf16x8v af = *(const bf16x8v*)(Au + (tm * 16 + (lane & 15)) * 40 + (lane >> 4) * 8);
                    bf16x8v bfv = *(const bf16x8v*)(Bu + (tn * 16 + (lane & 15)) * 40 + (lane >> 4) * 8);
                    acc[j] = __builtin_amdgcn_mfma_f32_16x16x32_bf16(af, bfv, acc[j], 0, 0, 0);
                }
            }
            __syncthreads();
        }
        // scatter integer C to [81][49]
        #pragma unroll
        for (int j = 0; j < 5; ++j) {
            const int t = wv + 4 * j;
            if (t < 18) {
                const int tm = t / 3, tn = t % 3;
                const int col = tn * 16 + (lane & 15);
                #pragma unroll
                for (int r = 0; r < 4; ++r) {
                    const int row = tm * 16 + (lane >> 4) * 4 + r;
                    if (row < 81) U[C2IF + row * 49 + col] = acc[j][r];
                }
            }
        }
        __syncthreads();
        // pool(3,2) + bias + quant -> ACT2 codes [48][16]
        for (int id = tid; id < 768; id += 256) {
            const int ch = id >> 4, pp = id & 15, ph = pp >> 2, pw = pp & 3;
            float mx = -1e30f;
            #pragma unroll
            for (int r = 0; r < 3; ++r)
                #pragma unroll
                for (int c = 0; c < 3; ++c)
                    mx = fmaxf(mx, U[C2IF + ((2 * ph + r) * 9 + (2 * pw + c)) * 49 + ch]);
            U[ACT2F + ch * 16 + pp] = qcode(mx, U[B2CF + ch], p2, sa2);
        }
    }
    __syncthreads();

    // ---- P4: conv3 (all 64 ch, W3 bf16 codes in LDS) ----
    for (int i = tid; i < 6144; i += 256) U[W3F + i] = wsr[W3B + i];  // raw bits
    if (tid < 64) U[B3CF + tid] = wsr[B3C + tid];
    __syncthreads();
    if (tid < 192) {                         // (o, hq): 64*3, 3 cols each
        const int o = tid / 3, hq = tid % 3;
        const unsigned* w3u = (const unsigned*)(U + W3F);
        float a0 = 0.f, a1 = 0.f, a2 = 0.f;
        for (int ci = 0; ci < 48; ++ci) {
            const unsigned pa = w3u[o * 96 + ci * 2];        // w00,w01
            const unsigned pb = w3u[o * 96 + ci * 2 + 1];    // w10,w11
            const float w00 = bfbits(pa & 0xffffu), w01 = bfbits(pa >> 16);
            const float w10 = bfbits(pb & 0xffffu), w11 = bfbits(pb >> 16);
            const int xb = ACT2F + ci * 16;
            float r0[4], r1[4];
            #pragma unroll
            for (int c = 0; c < 4; ++c) {
                r0[c] = U[xb + hq * 4 + c];
                r1[c] = U[xb + (hq + 1) * 4 + c];
            }
            a0 = fmaf(r0[0], w00, a0); a0 = fmaf(r0[1], w01, a0);
            a0 = fmaf(r1[0], w10, a0); a0 = fmaf(r1[1], w11, a0);
            a1 = fmaf(r0[1], w00, a1); a1 = fmaf(r0[2], w01, a1);
            a1 = fmaf(r1[1], w10, a1); a1 = fmaf(r1[2], w11, a1);
            a2 = fmaf(r0[2], w00, a2); a2 = fmaf(r0[3], w01, a2);
            a2 = fmaf(r1[2], w10, a2); a2 = fmaf(r1[3], w11, a2);
        }
        const float bc = U[B3CF + o];
        U[ACT3F + o * 9 + hq * 3 + 0] = qcode(a0, bc, p3, sa3);
        U[ACT3F + o * 9 + hq * 3 + 1] = qcode(a1, bc, p3, sa3);
        U[ACT3F + o * 9 + hq * 3 + 2] = qcode(a2, bc, p3, sa3);
    }
    __syncthreads();

    // ---- P5: fc1 (576->128), bf16 code weights streamed from L2 ----
    {
        const int o = tid & 127, half = tid >> 7;
        const __hip_bfloat16* fwb = (const __hip_bfloat16*)(wsr + FW1B);
        float acc = 0.f;
        const int k0 = half * 288;
        for (int k = k0; k < k0 + 288; ++k)
            acc = fmaf(U[ACT3F + k], __bfloat162float(fwb[k * 128 + o]), acc);
        U[PF + tid] = acc;
    }
    __syncthreads();
    if (tid < 128) {
        const float C = U[PF + tid] + U[PF + 128 + tid];
        U[A4F + tid] = qcode(C, wsr[FB1C + tid], p4, sa4);
    }
    __syncthreads();

    // ---- P6: heads + final signed quant ----
    if (tid < 96) {
        const int d = tid >> 4, gq = tid & 15;
        const float* hw = (d < 4) ? (wsr + BWC + d * 128) : (wsr + CWC + (d - 4) * 128);
        float p = 0.f;
        #pragma unroll
        for (int k = 0; k < 8; ++k)
            p = fmaf(U[A4F + gq * 8 + k], hw[gq * 8 + k], p);
        U[PARTF + d * 16 + gq] = p;
    }
    __syncthreads();
    if (tid < 6) {
        float C = (tid < 4) ? wsr[BBC + tid] : wsr[CBC + (tid - 4)];
        for (int g = 0; g < 16; ++g) C += U[PARTF + tid * 16 + g];
        if (tid < 4) {
            const float val = C * pB;
            outp[(size_t)b * 4 + tid] = fminf(fmaxf(rintf(val / sab), -8.f), 7.f) * sab;
        } else {
            const float val = C * pC;
            outp[16384 + (size_t)b * 2 + (tid - 4)] =
                fminf(fmaxf(rintf(val / sac), -8.f), 7.f) * sac;
        }
    }
}

// ================= fallback: R7 self-contained kernel (proven) =================
__global__ __launch_bounds__(256) void k_net_fb(
    const void* __restrict__ x,
    const void* __restrict__ w1,  const void* __restrict__ b1,
    const void* __restrict__ w2,  const void* __restrict__ b2,
    const void* __restrict__ w3,  const void* __restrict__ b3,
    const void* __restrict__ fw1, const void* __restrict__ fb1,
    const void* __restrict__ bw,  const void* __restrict__ bb,
    const void* __restrict__ cw,  const void* __restrict__ cb,
    const void* __restrict__ s0p, const void* __restrict__ s1p,
    const void* __restrict__ s2p, const void* __restrict__ s3p,
    const void* __restrict__ s4p, const void* __restrict__ s5p,
    const void* __restrict__ s6p,
    float* __restrict__ outp)
{
    __shared__ float U[16000];
    __shared__ float swsh[8];
    __shared__ float sash[8];
    const int tid = threadIdx.x;
    const int b   = blockIdx.x;
    constexpr int RED = 0, XQ = 0, W1Q = 1728, B1Q = 2484, C1 = 2512;
    constexpr int ACT1 = 9288, WB = 0, C2 = 12676, ACT2 = 14620, ACT3 = 15388;
    constexpr int A4 = 0, PART = 128;

    if (tid == 0) {
        const unsigned short* hb = (const unsigned short*)w1;
        int zeros = 0, sane = 0;
        for (int i = 0; i < 64; ++i) {
            unsigned short u = hb[2 * i];
            float v = __uint_as_float(((unsigned int)u) << 16);
            float a = fabsf(v);
            if (a == 0.f) zeros++;
            else if (a > 1e-8f && a < 1e4f) sane++;
        }
        swsh[7] = (zeros < 40 && sane >= 40) ? 1.f : 0.f;
        const void* sp[7] = { s0p, s1p, s2p, s3p, s4p, s5p, s6p };
        for (int j = 0; j < 7; ++j) {
            float v = *(const float*)sp[j];
            float a = fabsf(v);
            if (!(a > 1e-6f && a < 1e6f)) {
                double d = *(const double*)sp[j];
                double ad = fabs(d);
                if (ad > 1e-6 && ad < 1e6) v = (float)d;
                else {
                    unsigned short u = *(const unsigned short*)sp[j];
                    v = __uint_as_float(((unsigned int)u) << 16);
                }
            }
            sash[j] = v;
        }
    }
    __syncthreads();
    const int isbf = swsh[7] > 0.5f;
    {
        const void* wp[6] = { w1, w2, w3, fw1, bw, cw };
        const int   wn[6] = { 756, 12096, 12288, 73728, 512, 256 };
        for (int j = 0; j < 6; ++j) {
            float m = 0.f;
            for (int i = tid; i < wn[j]; i += 256)
                m = fmaxf(m, fabsf(loadT(wp[j], i, isbf)));
            U[RED + tid] = m; __syncthreads();
            for (int o = 128; o > 0; o >>= 1) {
                if (tid < o) U[RED + tid] = fmaxf(U[RED + tid], U[RED + tid + o]);
                __syncthreads();
            }
            if (tid == 0) swsh[j] = U[RED] / 7.0f;
            __syncthreads();
        }
    }
    const float sa0 = sash[0], sa1 = sash[1], sa2 = sash[2], sa3 = sash[3];
    const float sa4 = sash[4], sab = sash[5], sac = sash[6];
    const float sw1s = swsh[0], sw2s = swsh[1], sw3s = swsh[2];
    const float sw4s = swsh[3], swbs = swsh[4], swcs = swsh[5];

    for (int i = tid; i < 1728; i += 256) {
        float v = loadT(x, (size_t)b * 1728 + i, isbf);
        U[XQ + i] = fminf(fmaxf(rintf(v / sa0), -8.f), 7.f) * sa0;
    }
    for (int i = tid; i < 756; i += 256) U[W1Q + i] = quantw(loadT(w1, i, isbf), sw1s);
    {
        const float den = sa0 * sw1s;
        for (int i = tid; i < 28; i += 256) U[B1Q + i] = qbias(loadT(b1, i, isbf), den);
    }
    __syncthreads();

    for (int g = 0; g < 2; ++g) {
        const int obase = g * 14;
        for (int idx = tid; idx < 308; idx += 256) {
            const int ol = idx / 22, r = idx % 22, o = obase + ol;
            for (int c = 0; c < 22; ++c) {
                float acc = 0.f;
                #pragma unroll
                for (int ci = 0; ci < 3; ++ci)
                    #pragma unroll
                    for (int kr = 0; kr < 3; ++kr)
                        #pragma unroll
                        for (int kc = 0; kc < 3; ++kc)
                            acc = fmaf(U[XQ + ci * 576 + (r + kr) * 24 + (c + kc)],
                                       U[W1Q + o * 27 + ci * 9 + kr * 3 + kc], acc);
                U[C1 + ol * 484 + r * 22 + c] = acc + U[B1Q + o];
            }
        }
        __syncthreads();
        for (int i = tid; i < 1694; i += 256) {
            const int ol = i / 121, rem = i % 121, ph = rem / 11, pw = rem % 11;
            const int r0 = 2 * ph, c0 = 2 * pw;
            const int r1 = min(r0 + 3, 22), c1 = min(c0 + 3, 22);
            float mx = -1e30f;
            for (int r = r0; r < r1; ++r)
                for (int c = c0; c < c1; ++c)
                    mx = fmaxf(mx, U[C1 + ol * 484 + r * 22 + c]);
            U[ACT1 + (obase + ol) * 121 + rem] = qrelu(mx, sa1);
        }
        __syncthreads();
    }

    for (int h = 0; h < 2; ++h) {
        const int obase = h * 24;
        for (int i = tid; i < 6048; i += 256)
            U[WB + i] = quantw(loadT(w2, (size_t)h * 6048 + i, isbf), sw2s);
        {
            const float den = sa1 * sw2s;
            for (int i = tid; i < 24; i += 256)
                U[WB + 6048 + i] = qbias(loadT(b2, obase + i, isbf), den);
        }
        __syncthreads();
        for (int idx = tid; idx < 216; idx += 256) {
            const int ol = idx / 9, r = idx % 9;
            for (int c = 0; c < 9; ++c) {
                float acc = 0.f;
                for (int ci = 0; ci < 28; ++ci)
                    #pragma unroll
                    for (int kr = 0; kr < 3; ++kr)
                        #pragma unroll
                        for (int kc = 0; kc < 3; ++kc)
                            acc = fmaf(U[ACT1 + ci * 121 + (r + kr) * 11 + (c + kc)],
                                       U[WB + ol * 252 + ci * 9 + kr * 3 + kc], acc);
                U[C2 + ol * 81 + r * 9 + c] = acc + U[WB + 6048 + ol];
            }
        }
        __syncthreads();
        for (int i = tid; i < 384; i += 256) {
            const int ol = i / 16, ph = (i % 16) / 4, pw = i % 4;
            float mx = -1e30f;
            #pragma unroll
            for (int r = 0; r < 3; ++r)
                #pragma unroll
                for (int c = 0; c < 3; ++c)
                    mx = fmaxf(mx, U[C2 + ol * 81 + (2 * ph + r) * 9 + (2 * pw + c)]);
            U[ACT2 + (obase + ol) * 16 + (i % 16)] = qrelu(mx, sa2);
        }
        __syncthreads();
    }

    for (int h = 0; h < 2; ++h) {
        const int obase = h * 32;
        for (int i = tid; i < 6144; i += 256)
            U[WB + i] = quantw(loadT(w3, (size_t)h * 6144 + i, isbf), sw3s);
        {
            const float den = sa2 * sw3s;
            for (int i = tid; i < 32; i += 256)
                U[WB + 6144 + i] = qbias(loadT(b3, obase + i, isbf), den);
        }
        __syncthreads();
        for (int idx = tid; idx < 288; idx += 256) {
            const int ol = idx / 9, hh = (idx % 9) / 3, ww = idx % 3;
            float acc = 0.f;
            for (int ci = 0; ci < 48; ++ci) {
                const int xb2 = ACT2 + ci * 16;
                const int wb2 = WB + ol * 192 + ci * 4;
                acc = fmaf(U[xb2 + hh * 4 + ww],           U[wb2 + 0], acc);
                acc = fmaf(U[xb2 + hh * 4 + ww + 1],       U[wb2 + 1], acc);
                acc = fmaf(U[xb2 + (hh + 1) * 4 + ww],     U[wb2 + 2], acc);
                acc = fmaf(U[xb2 + (hh + 1) * 4 + ww + 1], U[wb2 + 3], acc);
            }
            acc += U[WB + 6144 + ol];
            U[ACT3 + (obase + ol) * 9 + hh * 3 + ww] = qrelu(acc, sa3);
        }
        __syncthreads();
    }

    {
        const int wave = tid >> 6, lane = tid & 63;
        const float den = sa3 * sw4s;
        for (int oo = 0; oo < 32; ++oo) {
            const int o = wave * 32 + oo;
            float acc = 0.f;
            #pragma unroll
            for (int j = 0; j < 9; ++j) {
                const int f = lane + 64 * j;
                const int c = f / 9, fw = (f % 9) / 3, fh = f % 3;
                const float av = U[ACT3 + c * 9 + fh * 3 + fw];
                const float wv = quantw(loadT(fw1, (size_t)o * 576 + f, isbf), sw4s);
                acc = fmaf(av, wv, acc);
            }
            #pragma unroll
            for (int off = 32; off > 0; off >>= 1)
                acc += __shfl_down(acc, off);
            if (lane == 0) {
                acc += qbias(loadT(fb1, o, isbf), den);
                U[A4 + o] = qrelu(acc, sa4);
            }
        }
    }
    __syncthreads();

    if (tid < 96) {
        const int d = tid >> 4, g = tid & 15;
        const void* hw = (d < 4) ? bw : cw;
        const int row = (d < 4) ? d : d - 4;
        const float swh = (d < 4) ? swbs : swcs;
        float p = 0.f;
        #pragma unroll
        for (int k = 0; k < 8; ++k) {
            const int kk = g * 8 + k;
            p = fmaf(U[A4 + kk], quantw(loadT(hw, row * 128 + kk, isbf), swh), p);
        }
        U[PART + d * 16 + g] = p;
    }
    __syncthreads();
    if (tid < 6) {
        const int d = tid;
        float acc;
        if (d < 4) acc = qbias(loadT(bb, d, isbf), sa4 * swbs);
        else       acc = qbias(loadT(cb, d - 4, isbf), sa4 * swcs);
        for (int g = 0; g < 16; ++g) acc += U[PART + d * 16 + g];
        if (d < 4) outp[(size_t)b * 4 + d] = fminf(fmaxf(rintf(acc / sab), -8.f), 7.f) * sab;
        else outp[16384 + (size_t)b * 2 + (d - 4)] = fminf(fmaxf(rintf(acc / sac), -8.f), 7.f) * sac;
    }
}

extern "C" void kernel_launch(void* const* d_in, const int* in_sizes, int n_in,
                              void* d_out, int out_size, void* d_ws, size_t ws_size,
                              hipStream_t stream)
{
    float* out = (float*)d_out;
    const int expect[20] = { 7077888, 756, 28, 12096, 48, 12288, 64, 73728, 128,
                             512, 4, 256, 2, 1, 1, 1, 1, 1, 1, 1 };
    if (n_in < 20) { k_beacon<<<1, 64, 0, stream>>>(out, 9000.f); return; }
    for (int i = 0; i < 20; ++i)
        if (in_sizes[i] != expect[i]) {
            k_beacon<<<1, 64, 0, stream>>>(out, 2000.f + 10.f * i);
            return;
        }

    if (ws_size >= (size_t)100000 * sizeof(float)) {
        float* ws = (float*)d_ws;
        k_scale<<<35, 256, 0, stream>>>(
            d_in[1], d_in[3], d_in[5], d_in[7], d_in[9], d_in[11],
            d_in[13], d_in[14], d_in[15], d_in[16], d_in[17], d_in[18], d_in[19],
            ws);
        k_quant<<<34, 256, 0, stream>>>(
            d_in[1], d_in[2], d_in[3], d_in[4], d_in[5], d_in[6],
            d_in[7], d_in[8], d_in[9], d_in[10], d_in[11], d_in[12],
            ws);
        k_net<<<4096, 256, 0, stream>>>(d_in[0], ws, out);
    } else {
        k_net_fb<<<4096, 256, 0, stream>>>(
            d_in[0], d_in[1], d_in[2], d_in[3], d_in[4], d_in[5], d_in[6],
            d_in[7], d_in[8], d_in[9], d_in[10], d_in[11], d_in[12],
            d_in[13], d_in[14], d_in[15], d_in[16], d_in[17], d_in[18], d_in[19],
            out);
    }
}